// Round 9
// baseline (481.237 us; speedup 1.0000x reference)
//
#include <hip/hip_runtime.h>
#include <hip/hip_bf16.h>
#include <stdint.h>

#define DEV __device__ __forceinline__

typedef __attribute__((ext_vector_type(8))) short bf16x8;
typedef __attribute__((ext_vector_type(4))) short short4v;
typedef __attribute__((ext_vector_type(4))) float f32x4;

static constexpr int LL = 4096;
static constexpr int NH = 16;
static constexpr int HD = 64;
static constexpr int DM = 1024;
static constexpr int NL = 128;    // landmarks
static constexpr int BH = 64;     // B*NH
static constexpr int NSPLIT = 16; // split-K factor for k3v flash
static constexpr float QK_SCALE = 0.35355339059327379f;  // 1/sqrt(sqrt(64))

DEV short f2bf(float f) {
  union { __hip_bfloat16 h; short s; } u;
  u.h = __float2bfloat16(f);
  return u.s;
}
DEV float bf2f(unsigned short s) {
  union { unsigned u; float f; } u;
  u.u = ((unsigned)s) << 16;
  return u.f;
}
DEV float clampf(float v) {  // also scrubs NaN (AMD IEEE min/max return the non-NaN operand)
  return fminf(fmaxf(v, -1e6f), 1e6f);
}

DEV f32x4 mfma16(bf16x8 a, bf16x8 b, f32x4 c) {
  return __builtin_amdgcn_mfma_f32_16x16x32_bf16(a, b, c, 0, 0, 0);
}

DEV void gl2lds16(const void* g, void* l) {
  __builtin_amdgcn_global_load_lds(
      (const __attribute__((address_space(1))) void*)g,
      (__attribute__((address_space(3))) void*)l, 16, 0, 0);
}

// hi/lo bf16 split of one fp32 value (truncate-to-bf16 hi, rounded residual lo)
DEV void split1(float f, short& hi, short& lo) {
  unsigned u = __float_as_uint(f);
  hi = (short)(u >> 16);
  lo = f2bf(f - __uint_as_float(u & 0xffff0000u));
}

// split 8 fp32 values into hi/lo bf16x8 vectors
DEV void split8(const float* av, bf16x8& hv, bf16x8& lv) {
#pragma unroll
  for (int e = 0; e < 8; e++) {
    short hi, lo;
    split1(av[e], hi, lo);
    hv[e] = hi;
    lv[e] = lo;
  }
}

// ---------------------------------------------------------------------------
// Kernel 0: dtype probe.  flags[i]=1 if input i looks like fp32.
// ---------------------------------------------------------------------------
__global__ __launch_bounds__(256) void probe_kernel(
    const unsigned short* p0, const unsigned short* p1, const unsigned short* p2,
    const unsigned short* p3, const unsigned short* p4, const unsigned short* p5,
    const unsigned short* p6, int* flags)
{
  const unsigned short* ps[7] = {p0, p1, p2, p3, p4, p5, p6};
  const unsigned short* p = ps[blockIdx.x];
  const int t = threadIdx.x;
  __shared__ int cnt;
  if (t == 0) cnt = 0;
  __syncthreads();
  int c = 0;
  for (int i = t; i < 512; i += 256) {
    unsigned e = (p[2 * i] >> 7) & 0xFF;
    if (e > 90 && e < 160) c++;
  }
  atomicAdd(&cnt, c);
  __syncthreads();
  if (t == 0) flags[blockIdx.x] = (cnt < 358) ? 1 : 0;  // <70% sane => fp32
}

// ---------------------------------------------------------------------------
// Kernel 0b: convert x to bf16 (or copy if already bf16).  n8 = elems/8.
// ---------------------------------------------------------------------------
__global__ __launch_bounds__(256) void cvtx_kernel(
    const void* __restrict__ src, const int* __restrict__ flags, int fidx,
    unsigned short* __restrict__ dst, int n8)
{
  const int f32 = flags[fidx];
  for (int i = blockIdx.x * 256 + threadIdx.x; i < n8; i += gridDim.x * 256) {
    if (f32) {
      const float* s = (const float*)src + (size_t)i * 8;
      f32x4 a = *(const f32x4*)s;
      f32x4 b = *(const f32x4*)(s + 4);
      bf16x8 o;
      o[0] = f2bf(a[0]); o[1] = f2bf(a[1]); o[2] = f2bf(a[2]); o[3] = f2bf(a[3]);
      o[4] = f2bf(b[0]); o[5] = f2bf(b[1]); o[6] = f2bf(b[2]); o[7] = f2bf(b[3]);
      *(bf16x8*)(dst + (size_t)i * 8) = o;
    } else {
      *(bf16x8*)(dst + (size_t)i * 8) =
          *(const bf16x8*)((const unsigned short*)src + (size_t)i * 8);
    }
  }
}

// ---------------------------------------------------------------------------
// Kernel 0c: convert Wq/Wk/Wv -> packed bf16 Wb[3][1024][1024], biases -> fp32.
// ---------------------------------------------------------------------------
__global__ __launch_bounds__(256) void cvtw_kernel(
    const void* __restrict__ Wq, const void* __restrict__ Wk, const void* __restrict__ Wv,
    const void* __restrict__ bq, const void* __restrict__ bk, const void* __restrict__ bv,
    const int* __restrict__ flags,
    unsigned short* __restrict__ Wb, float* __restrict__ bb)
{
  const int bid = blockIdx.x, t = threadIdx.x;
  if (bid < 1536) {
    const int q = bid / 512;
    const int i = (bid % 512) * 256 + t;     // elem8 index within one W
    const void* src = (q == 0) ? Wq : ((q == 1) ? Wk : Wv);
    unsigned short* dst = Wb + (size_t)q * DM * DM;
    if (flags[1 + 2 * q]) {
      const float* s = (const float*)src + (size_t)i * 8;
      f32x4 a = *(const f32x4*)s;
      f32x4 b = *(const f32x4*)(s + 4);
      bf16x8 o;
      o[0] = f2bf(a[0]); o[1] = f2bf(a[1]); o[2] = f2bf(a[2]); o[3] = f2bf(a[3]);
      o[4] = f2bf(b[0]); o[5] = f2bf(b[1]); o[6] = f2bf(b[2]); o[7] = f2bf(b[3]);
      *(bf16x8*)(dst + (size_t)i * 8) = o;
    } else {
      *(bf16x8*)(dst + (size_t)i * 8) =
          *(const bf16x8*)((const unsigned short*)src + (size_t)i * 8);
    }
  } else {
    for (int i = t; i < 3 * DM; i += 256) {
      int q = i >> 10, idx = i & 1023;
      const void* src = (q == 0) ? bq : ((q == 1) ? bk : bv);
      bb[i] = flags[2 + 2 * q] ? ((const float*)src)[idx]
                               : bf2f(((const unsigned short*)src)[idx]);
    }
  }
}

// ---------------------------------------------------------------------------
// Kernel 1 (BK=64, two-panel LDS): one output (Q|K|V) x one 128-col tile per
// block.  Landmark means written in BOTH fp32 (k2) and bf16 (k3v/final) —
// the former lmcvt kernel is folded here.
// ---------------------------------------------------------------------------
__global__ __launch_bounds__(256, 2) void proj_kernel(
    const unsigned short* __restrict__ xb,
    const unsigned short* __restrict__ Wb,
    const float* __restrict__ bb,
    unsigned short* __restrict__ Qo, unsigned short* __restrict__ Ko,
    unsigned short* __restrict__ Vo,
    float* __restrict__ Qlm, float* __restrict__ Klm,
    unsigned short* __restrict__ Qlmb, unsigned short* __restrict__ Klmb)
{
  __shared__ __align__(16) short As[2][128 * 32];
  __shared__ __align__(16) short Bs[2][128 * 32];

  const int t = threadIdx.x;
  const int w = t >> 6;
  const int l = t & 63;
  const int lane16 = l & 15, lgrp = l >> 4;

  const int bid = blockIdx.x;
  const int mt = bid & 127;
  const int nt = bid >> 7;
  const int which = nt >> 3;  // 0=Q 1=K 2=V
  const int m0 = mt * 128;
  const int ncol0 = (nt & 7) * 128;

  unsigned short* outp = (which == 0) ? Qo : ((which == 1) ? Ko : Vo);
  const float scl = (which == 2) ? 1.0f : QK_SCALE;

  const int srow = w * 16 + (l >> 2);
  const int skc = (l & 3) * 8;
  const unsigned short* gA = xb + (size_t)(m0 + srow) * DM + skc;
  const unsigned short* gB = Wb + (size_t)which * DM * DM + (size_t)(ncol0 + srow) * DM + skc;
  short* lA0 = As[0] + w * 512;  // wave-uniform base for gl2lds (HW adds lane*16B)
  short* lA1 = As[1] + w * 512;
  short* lB0 = Bs[0] + w * 512;
  short* lB1 = Bs[1] + w * 512;

  const int wm = (w >> 1) * 64;
  const int wn = (w & 1) * 64;

  f32x4 acc[4][4];
#pragma unroll
  for (int i = 0; i < 4; i++)
#pragma unroll
    for (int j = 0; j < 4; j++) acc[i][j] = f32x4{0.f, 0.f, 0.f, 0.f};

  for (int kk = 0; kk < DM; kk += 64) {
    gl2lds16(gA + kk, lA0);
    gl2lds16(gA + kk + 64 * DM, lA0 + 2048);
    gl2lds16(gA + kk + 32, lA1);
    gl2lds16(gA + kk + 32 + 64 * DM, lA1 + 2048);
    gl2lds16(gB + kk, lB0);
    gl2lds16(gB + kk + 64 * DM, lB0 + 2048);
    gl2lds16(gB + kk + 32, lB1);
    gl2lds16(gB + kk + 32 + 64 * DM, lB1 + 2048);
    __syncthreads();
#pragma unroll
    for (int kc = 0; kc < 2; kc++) {
      bf16x8 af[4], bfv[4];
#pragma unroll
      for (int i = 0; i < 4; i++) {
        af[i]  = *(const bf16x8*)&As[kc][(wm + i * 16 + lane16) * 32 + lgrp * 8];
        bfv[i] = *(const bf16x8*)&Bs[kc][(wn + i * 16 + lane16) * 32 + lgrp * 8];
      }
#pragma unroll
      for (int i = 0; i < 4; i++)
#pragma unroll
        for (int j = 0; j < 4; j++)
          acc[i][j] = mfma16(af[i], bfv[j], acc[i][j]);
    }
    __syncthreads();
  }

  const int b = m0 >> 12;
  const int hh = (ncol0 + wn) >> 6;
  float bv4[4];
#pragma unroll
  for (int j = 0; j < 4; j++)
    bv4[j] = bb[which * DM + ncol0 + wn + j * 16 + lane16];

  float seg[2][4];
#pragma unroll
  for (int s = 0; s < 2; s++)
#pragma unroll
    for (int j = 0; j < 4; j++) seg[s][j] = 0.f;

#pragma unroll
  for (int i = 0; i < 4; i++) {
#pragma unroll
    for (int j = 0; j < 4; j++) {
#pragma unroll
      for (int r = 0; r < 4; r++) {
        float v = (acc[i][j][r] + bv4[j]) * scl;
        int row = wm + i * 16 + lgrp * 4 + r;
        int li = (m0 + row) & 4095;
        int dd = (wn + j * 16 + lane16) & 63;
        outp[(((size_t)(b * NH + hh)) * LL + li) * HD + dd] = (unsigned short)f2bf(v);
        seg[i >> 1][j] += v;
      }
    }
  }
  if (which < 2) {
    float* lmb = (which == 0) ? Qlm : Klm;
    unsigned short* lmbb = (which == 0) ? Qlmb : Klmb;
#pragma unroll
    for (int s = 0; s < 2; s++) {
#pragma unroll
      for (int j = 0; j < 4; j++) {
        float ssum = seg[s][j];
        ssum += __shfl_xor(ssum, 16, 64);
        ssum += __shfl_xor(ssum, 32, 64);
        if (lgrp == 0) {
          int m = ((m0 + wm + s * 32) & 4095) >> 5;
          int dd = (wn + j * 16 + lane16) & 63;
          float mv = clampf(ssum * (1.0f / 32.0f));
          size_t idx = (((size_t)(b * NH + hh)) * NL + m) * HD + dd;
          lmb[idx] = mv;
          lmbb[idx] = (unsigned short)f2bf(mv);
        }
      }
    }
  }
}

// ---------------------------------------------------------------------------
// Kernel 3: kernel_2 = softmax(Qlm @ Klm^T) fp32, re-partitioned (512 blocks,
// dots cached in registers).  Partial colsums -> global via atomicAdd.
// ---------------------------------------------------------------------------
__global__ __launch_bounds__(256, 1) void k2_kernel(
    const float* __restrict__ Qlm, const float* __restrict__ Klm,
    float* __restrict__ k2, float* __restrict__ colsum_g)
{
  __shared__ float cs[NL];
  const int bid = blockIdx.x;
  const int bh = bid >> 3;
  const int rc = bid & 7;            // 16-row chunk
  const int t = threadIdx.x;
  const int r = t >> 4;              // local row 0..15
  const int c = t & 15;              // col lane 0..15
  const int row = rc * 16 + r;
  const float* Q = Qlm + ((size_t)bh * NL + row) * HD;
  const float* K = Klm + (size_t)bh * NL * HD;
  float* k2p = k2 + (size_t)bh * NL * NL;

  for (int i = t; i < NL; i += 256) cs[i] = 0.f;

  f32x4 q4[16];
#pragma unroll
  for (int d = 0; d < 16; d++) q4[d] = *(const f32x4*)&Q[d * 4];

  float dots[8];
#pragma unroll
  for (int g = 0; g < 8; g++) {
    const float* kr = K + (size_t)(c + g * 16) * HD;
    float s = 0.f;
#pragma unroll
    for (int d = 0; d < 16; d++) {
      f32x4 k4 = *(const f32x4*)&kr[d * 4];
      s += q4[d][0] * k4[0];
      s += q4[d][1] * k4[1];
      s += q4[d][2] * k4[2];
      s += q4[d][3] * k4[3];
    }
    dots[g] = s;
  }

  float mx = dots[0];
#pragma unroll
  for (int g = 1; g < 8; g++) mx = fmaxf(mx, dots[g]);
  mx = fmaxf(mx, __shfl_xor(mx, 1, 16));
  mx = fmaxf(mx, __shfl_xor(mx, 2, 16));
  mx = fmaxf(mx, __shfl_xor(mx, 4, 16));
  mx = fmaxf(mx, __shfl_xor(mx, 8, 16));

  float sum = 0.f;
#pragma unroll
  for (int g = 0; g < 8; g++) {
    float e = __expf(dots[g] - mx);
    dots[g] = e;
    sum += e;
  }
  sum += __shfl_xor(sum, 1, 16);
  sum += __shfl_xor(sum, 2, 16);
  sum += __shfl_xor(sum, 4, 16);
  sum += __shfl_xor(sum, 8, 16);
  const float inv = 1.0f / fmaxf(sum, 1e-30f);

  __syncthreads();  // cs init complete
#pragma unroll
  for (int g = 0; g < 8; g++) {
    float p = dots[g] * inv;
    k2p[(size_t)row * NL + c + g * 16] = p;
    atomicAdd(&cs[c + g * 16], p);
  }
  __syncthreads();
  for (int i = t; i < NL; i += 256) atomicAdd(&colsum_g[bh * NL + i], cs[i]);
}

// ---------------------------------------------------------------------------
// Kernel 3b: alpha = max over all (bh, col) colsums.  Single block.
// ---------------------------------------------------------------------------
__global__ __launch_bounds__(256) void alpha_kernel(
    const float* __restrict__ colsum_g, unsigned* __restrict__ alpha_bits)
{
  __shared__ float wm[4];
  const int t = threadIdx.x;
  float m = 0.f;  // colsums are sums of softmax probs >= 0
  for (int i = t; i < BH * NL; i += 256) m = fmaxf(m, colsum_g[i]);
#pragma unroll
  for (int o = 1; o < 64; o <<= 1) m = fmaxf(m, __shfl_xor(m, o, 64));
  if ((t & 63) == 0) wm[t >> 6] = m;
  __syncthreads();
  if (t == 0)
    *alpha_bits = __float_as_uint(fmaxf(fmaxf(wm[0], wm[1]), fmaxf(wm[2], wm[3])));
}

// ---------------------------------------------------------------------------
// Kernel 4 (SPLIT-K, NSPLIT=16): partial flash over L-range [sp*256, +256).
// Combine is folded into ns_kernel's tail (ns is the sole k3v consumer).
// ---------------------------------------------------------------------------
__global__ __launch_bounds__(256, 1) void k3v_kernel(
    const unsigned short* __restrict__ Qlmb, const unsigned short* __restrict__ K,
    const unsigned short* __restrict__ V,
    float* __restrict__ op, float* __restrict__ mp, float* __restrict__ lp)
{
  constexpr int LT = 64;
  constexpr int ST = 72;
  __shared__ __align__(16) short q_s[NL * ST];
  __shared__ __align__(16) short k_s[LT * ST];
  __shared__ __align__(16) short vt_s[HD * ST];
  __shared__ __align__(16) short p_s[NL * ST];

  const int bid = blockIdx.x;
  const int bh = bid >> 4;           // NSPLIT = 16
  const int sp = bid & (NSPLIT - 1);
  const int t = threadIdx.x;
  const int w = t >> 6, l = t & 63;
  const int lane16 = l & 15, lgrp = l >> 4;
  const int wm = w * 32;
  const unsigned short* Kp = K + (size_t)bh * LL * HD;
  const unsigned short* Vp = V + (size_t)bh * LL * HD;

  for (int i = t; i < NL * HD / 4; i += 256) {
    int flat = i * 4, rr = flat >> 6, dd = flat & 63;
    *(uint2*)&q_s[rr * ST + dd] = *(const uint2*)&Qlmb[(size_t)bh * NL * HD + flat];
  }

  f32x4 oacc[2][4];
  float mrun[2][4], lrun[2][4];
#pragma unroll
  for (int i = 0; i < 2; i++)
#pragma unroll
    for (int j = 0; j < 4; j++) oacc[i][j] = f32x4{0.f, 0.f, 0.f, 0.f};
#pragma unroll
  for (int i = 0; i < 2; i++)
#pragma unroll
    for (int r = 0; r < 4; r++) { mrun[i][r] = -3.0e38f; lrun[i][r] = 0.f; }

  constexpr int TPS = LL / LT / NSPLIT;  // tiles per split = 4
  for (int lt = sp * TPS; lt < (sp + 1) * TPS; lt++) {
    const int l0 = lt * LT;
    for (int i = t; i < LT * HD / 4; i += 256) {
      int flat = i * 4, rr = flat >> 6, dd = flat & 63;
      *(uint2*)&k_s[rr * ST + dd] = *(const uint2*)&Kp[(size_t)(l0 + rr) * HD + dd];
      uint2 raw = *(const uint2*)&Vp[(size_t)(l0 + rr) * HD + dd];
      vt_s[(dd + 0) * ST + rr] = (short)(raw.x & 0xffff);
      vt_s[(dd + 1) * ST + rr] = (short)(raw.x >> 16);
      vt_s[(dd + 2) * ST + rr] = (short)(raw.y & 0xffff);
      vt_s[(dd + 3) * ST + rr] = (short)(raw.y >> 16);
    }
    __syncthreads();

    f32x4 sacc[2][4];
#pragma unroll
    for (int i = 0; i < 2; i++)
#pragma unroll
      for (int j = 0; j < 4; j++) sacc[i][j] = f32x4{0.f, 0.f, 0.f, 0.f};
#pragma unroll
    for (int kc = 0; kc < 2; kc++) {
      bf16x8 aq[2];
#pragma unroll
      for (int i = 0; i < 2; i++)
        aq[i] = *(const bf16x8*)&q_s[(wm + i * 16 + lane16) * ST + kc * 32 + lgrp * 8];
#pragma unroll
      for (int j = 0; j < 4; j++) {
        bf16x8 bk = *(const bf16x8*)&k_s[(j * 16 + lane16) * ST + kc * 32 + lgrp * 8];
#pragma unroll
        for (int i = 0; i < 2; i++) sacc[i][j] = mfma16(aq[i], bk, sacc[i][j]);
      }
    }

#pragma unroll
    for (int i = 0; i < 2; i++) {
#pragma unroll
      for (int r = 0; r < 4; r++) {
        float tm = fmaxf(fmaxf(sacc[i][0][r], sacc[i][1][r]),
                         fmaxf(sacc[i][2][r], sacc[i][3][r]));
        tm = fmaxf(tm, __shfl_xor(tm, 1, 16));
        tm = fmaxf(tm, __shfl_xor(tm, 2, 16));
        tm = fmaxf(tm, __shfl_xor(tm, 4, 16));
        tm = fmaxf(tm, __shfl_xor(tm, 8, 16));
        float mnew = fmaxf(mrun[i][r], tm);
        float al = __expf(mrun[i][r] - mnew);
        float rs = 0.f;
#pragma unroll
        for (int j = 0; j < 4; j++) {
          float e = __expf(sacc[i][j][r] - mnew);
          sacc[i][j][r] = e;
          rs += e;
        }
        rs += __shfl_xor(rs, 1, 16);
        rs += __shfl_xor(rs, 2, 16);
        rs += __shfl_xor(rs, 4, 16);
        rs += __shfl_xor(rs, 8, 16);
        lrun[i][r] = lrun[i][r] * al + rs;
        mrun[i][r] = mnew;
#pragma unroll
        for (int j = 0; j < 4; j++) oacc[i][j][r] *= al;
        int row = wm + i * 16 + lgrp * 4 + r;
#pragma unroll
        for (int j = 0; j < 4; j++)
          p_s[row * ST + j * 16 + lane16] = f2bf(sacc[i][j][r]);
      }
    }
    __syncthreads();

#pragma unroll
    for (int kc = 0; kc < 2; kc++) {
      bf16x8 ap[2];
#pragma unroll
      for (int i = 0; i < 2; i++)
        ap[i] = *(const bf16x8*)&p_s[(wm + i * 16 + lane16) * ST + kc * 32 + lgrp * 8];
#pragma unroll
      for (int j = 0; j < 4; j++) {
        bf16x8 bv = *(const bf16x8*)&vt_s[(j * 16 + lane16) * ST + kc * 32 + lgrp * 8];
#pragma unroll
        for (int i = 0; i < 2; i++) oacc[i][j] = mfma16(ap[i], bv, oacc[i][j]);
      }
    }
    __syncthreads();
  }

  // unnormalized partial out + per-row m,l
  float* opp = op + ((size_t)(bh * NSPLIT + sp)) * NL * HD;
#pragma unroll
  for (int i = 0; i < 2; i++)
#pragma unroll
    for (int j = 0; j < 4; j++)
#pragma unroll
      for (int r = 0; r < 4; r++) {
        int row = wm + i * 16 + lgrp * 4 + r;
        int dd = j * 16 + lane16;
        opp[(size_t)row * HD + dd] = oacc[i][j][r];
      }
  if (lane16 == 0) {
    const size_t base = (size_t)(bh * NSPLIT + sp) * NL;
#pragma unroll
    for (int i = 0; i < 2; i++)
#pragma unroll
      for (int r = 0; r < 4; r++) {
        int row = wm + i * 16 + lgrp * 4 + r;
        mp[base + row] = mrun[i][r];
        lp[base + row] = lrun[i][r];
      }
  }
}

// ---------------------------------------------------------------------------
// Kernel 5: Newton-Schulz pseudo-inverse, 6 iterations, hi/lo-split bf16 MFMA,
// fully LDS-resident (8-barrier/iter form — the proven register-friendly
// structure; round-7's merged-loop variant spilled).  Tail: inline flash
// combine of the k3v split partials + W2 = Vinv @ k3v.
// ---------------------------------------------------------------------------
__global__ __launch_bounds__(512, 1) void ns_kernel(
    const float* __restrict__ k2, const unsigned* __restrict__ alpha_bits,
    const float* __restrict__ op, const float* __restrict__ mp,
    const float* __restrict__ lp, unsigned short* __restrict__ w2t)
{
  constexpr int VST = 132;   // fp32 row stride: 132 mod 32 = 4 -> 2-way (free) banks
  constexpr int BST = 136;   // bf16 row stride: 68 dwords -> uniform b128 starts
  __shared__ __align__(16) float Vf[NL * VST];    // 67.6 KB
  __shared__ __align__(16) short Bth[NL * BST];   // 34.8 KB
  __shared__ __align__(16) short Btl[NL * BST];   // 34.8 KB  (total 137 KB < 160 KB)

  const int bh = blockIdx.x, t = threadIdx.x;
  const int w = t >> 6, l = t & 63;
  const int lane16 = l & 15, lgrp = l >> 4;
  const float* K2 = k2 + (size_t)bh * NL * NL;

  // --- K2 A-fragments (hi/lo) into registers, once (64 VGPRs) ---
  bf16x8 k2hi[4], k2lo[4];
#pragma unroll
  for (int kk = 0; kk < 4; kk++) {
    const float* ap = K2 + (size_t)(w * 16 + lane16) * NL + kk * 32 + lgrp * 8;
    f32x4 a0 = *(const f32x4*)ap;
    f32x4 a1 = *(const f32x4*)(ap + 4);
    float av[8] = {a0[0], a0[1], a0[2], a0[3], a1[0], a1[1], a1[2], a1[3]};
    split8(av, k2hi[kk], k2lo[kk]);
  }

  // --- init: V = clamp(K2^T * inva) -> Vf row-major; Bt = V^T = clamp(K2*inva)
  const float inva = 1.0f / fmaxf(__uint_as_float(*alpha_bits), 1e-30f);
  for (int i = t; i < NL * NL; i += 512) {
    int rr = i >> 7, cc = i & 127;
    float v = clampf(K2[(size_t)cc * NL + rr] * inva);
    Vf[rr * VST + cc] = v;
    short hi, lo; split1(v, hi, lo);
    Bth[cc * BST + rr] = hi;
    Btl[cc * BST + rr] = lo;
  }
  __syncthreads();

  f32x4 macc[8], vacc[8];

  // macc = A @ B  with A-fragments in registers, B = Bt (transposed hi/lo)
  auto mmA = [&](const bf16x8* ahi, const bf16x8* alo) {
#pragma unroll
    for (int j = 0; j < 8; j++) macc[j] = f32x4{0.f, 0.f, 0.f, 0.f};
#pragma unroll
    for (int kk = 0; kk < 4; kk++) {
#pragma unroll
      for (int j = 0; j < 8; j++) {
        const int bo = (j * 16 + lane16) * BST + kk * 32 + lgrp * 8;
        bf16x8 bh_ = *(const bf16x8*)&Bth[bo];
        bf16x8 bl_ = *(const bf16x8*)&Btl[bo];
        macc[j] = mfma16(alo[kk], bh_, macc[j]);
        macc[j] = mfma16(ahi[kk], bl_, macc[j]);
        macc[j] = mfma16(ahi[kk], bh_, macc[j]);
      }
    }
  };

  // macc = Vf @ B (A rows = this wave's 16 rows of Vf, split on the fly)
  auto mmV = [&]() {
    bf16x8 ahi[4], alo[4];
#pragma unroll
    for (int kk = 0; kk < 4; kk++) {
      const float* ap = &Vf[(w * 16 + lane16) * VST + kk * 32 + lgrp * 8];
      f32x4 a0 = *(const f32x4*)ap;
      f32x4 a1 = *(const f32x4*)(ap + 4);
      float av[8] = {a0[0], a0[1], a0[2], a0[3], a1[0], a1[1], a1[2], a1[3]};
      split8(av, ahi[kk], alo[kk]);
    }
    mmA(ahi, alo);
  };

  // Bt <- clamp(macc)^T  (packed b64 writes: 4 consecutive rows per lane)
  auto writeBt = [&]() {
#pragma unroll
    for (int j = 0; j < 8; j++) {
      short4v hv, lv;
#pragma unroll
      for (int r = 0; r < 4; r++) {
        float c = clampf(macc[j][r]);
        short hi, lo; split1(c, hi, lo);
        hv[r] = hi; lv[r] = lo;
      }
      const int base = (j * 16 + lane16) * BST + w * 16 + lgrp * 4;
      *(short4v*)&Bth[base] = hv;
      *(short4v*)&Btl[base] = lv;
    }
  };

  for (int it = 0; it < 6; it++) {
    // KV = K2 @ V   (B = Bt holding V^T)
    mmA(k2hi, k2lo);
    __syncthreads();              // all waves done reading Bt(V^T)
    writeBt();                    // Bt <- KV^T (clamped), B for mm2..mm4
    __syncthreads();

    // M1 = V @ KV ; vacc = 3.25*V - 3.75*M1
    mmV();
#pragma unroll
    for (int j = 0; j < 8; j++)
#pragma unroll
      for (int r = 0; r < 4; r++)
        vacc[j][r] = 3.25f * Vf[(w * 16 + lgrp * 4 + r) * VST + j * 16 + lane16]
                   - 3.75f * macc[j][r];
    __syncthreads();
#pragma unroll
    for (int j = 0; j < 8; j++)
#pragma unroll
      for (int r = 0; r < 4; r++)
        Vf[(w * 16 + lgrp * 4 + r) * VST + j * 16 + lane16] = clampf(macc[j][r]);
    __syncthreads();

    // M2 = M1 @ KV ; vacc += 1.75*M2
    mmV();
#pragma unroll
    for (int j = 0; j < 8; j++)
#pragma unroll
      for (int r = 0; r < 4; r++) vacc[j][r] += 1.75f * macc[j][r];
    __syncthreads();
#pragma unroll
    for (int j = 0; j < 8; j++)
#pragma unroll
      for (int r = 0; r < 4; r++)
        Vf[(w * 16 + lgrp * 4 + r) * VST + j * 16 + lane16] = clampf(macc[j][r]);
    __syncthreads();

    // M3 = M2 @ KV ; V_new = clamp(vacc - 0.25*M3) -> Vf + Bt (for next iter)
    mmV();
    __syncthreads();              // all waves done reading Bt(KV^T) + Vf(M2)
#pragma unroll
    for (int j = 0; j < 8; j++) {
      short4v hv, lv;
#pragma unroll
      for (int r = 0; r < 4; r++) {
        float v = clampf(vacc[j][r] - 0.25f * macc[j][r]);
        Vf[(w * 16 + lgrp * 4 + r) * VST + j * 16 + lane16] = v;
        short hi, lo; split1(v, hi, lo);
        hv[r] = hi; lv[r] = lo;
      }
      const int base = (j * 16 + lane16) * BST + w * 16 + lgrp * 4;
      *(short4v*)&Bth[base] = hv;
      *(short4v*)&Btl[base] = lv;
    }
    __syncthreads();
  }

  // ------- tail: inline flash-combine of k3v partials -> Bt (hi/lo, k3v^T),
  // then W2 = Vinv @ k3v ;  w2t[dd][m] = W2[m][dd] -------
  const float* opp = op + (size_t)bh * NSPLIT * NL * HD;
  const float* mpp = mp + (size_t)bh * NSPLIT * NL;
  const float* lpp = lp + (size_t)bh * NSPLIT * NL;
  for (int i = t; i < NL * HD; i += 512) {
    int rr = i >> 6, dd = i & 63;
    float ms[NSPLIT];
    float m = -3.0e38f;
#pragma unroll
    for (int s = 0; s < NSPLIT; s++) {
      ms[s] = mpp[(size_t)s * NL + rr];
      m = fmaxf(m, ms[s]);
    }
    float o = 0.f, lt_ = 0.f;
#pragma unroll
    for (int s = 0; s < NSPLIT; s++) {
      float sc = __expf(ms[s] - m);
      lt_ += lpp[(size_t)s * NL + rr] * sc;
      o += opp[((size_t)s * NL + rr) * HD + dd] * sc;
    }
    float f = clampf(o / fmaxf(lt_, 1e-30f));
    short hi, lo; split1(f, hi, lo);
    Bth[dd * BST + rr] = hi;
    Btl[dd * BST + rr] = lo;
  }
  __syncthreads();

  const int wr = (w & 3);    // dd row-tile (4 x 16 = 64 rows)
  const int wc = (w >> 2);   // m half (2 x 64 cols)
  f32x4 oacc[4];
#pragma unroll
  for (int j = 0; j < 4; j++) oacc[j] = f32x4{0.f, 0.f, 0.f, 0.f};
#pragma unroll
  for (int kk = 0; kk < 4; kk++) {
    const int ao = (wr * 16 + lane16) * BST + kk * 32 + lgrp * 8;
    bf16x8 ahi = *(const bf16x8*)&Bth[ao];
    bf16x8 alo = *(const bf16x8*)&Btl[ao];
#pragma unroll
    for (int j = 0; j < 4; j++) {
      const float* bp = &Vf[((wc * 4 + j) * 16 + lane16) * VST + kk * 32 + lgrp * 8];
      f32x4 b0 = *(const f32x4*)bp;
      f32x4 b1 = *(const f32x4*)(bp + 4);
      float bvv[8] = {b0[0], b0[1], b0[2], b0[3], b1[0], b1[1], b1[2], b1[3]};
      bf16x8 bhv, blv;
      split8(bvv, bhv, blv);
      oacc[j] = mfma16(alo, bhv, oacc[j]);
      oacc[j] = mfma16(ahi, blv, oacc[j]);
      oacc[j] = mfma16(ahi, bhv, oacc[j]);
    }
  }
  unsigned short* outp = w2t + (size_t)bh * HD * NL;
#pragma unroll
  for (int j = 0; j < 4; j++)
#pragma unroll
    for (int r = 0; r < 4; r++) {
      int dd = wr * 16 + lgrp * 4 + r;
      int m  = (wc * 4 + j) * 16 + lane16;
      outp[(size_t)dd * NL + m] = (unsigned short)f2bf(clampf(oacc[j][r]));
    }
}

// ---------------------------------------------------------------------------
// Kernel 7: out = softmax_rows(Q @ Klm^T) @ W2 -> FP32 output.
// ---------------------------------------------------------------------------
__global__ __launch_bounds__(256, 2) void final_kernel(
    const unsigned short* __restrict__ Q, const unsigned short* __restrict__ Klmb,
    const unsigned short* __restrict__ w2t, float* __restrict__ outp)
{
  constexpr int KSD = 72;
  constexpr int PSD = 136;
  __shared__ __align__(16) short klm_s[NL * KSD];
  __shared__ __align__(16) short p_s[NL * PSD];

  const int bid = blockIdx.x;
  const int bh = bid >> 5, lt = bid & 31;
  const int l0 = lt * NL;
  const int t = threadIdx.x, w = t >> 6, l = t & 63;
  const int lane16 = l & 15, lgrp = l >> 4;
  const int wm = w * 32;
  const unsigned short* Qp = Q + (size_t)bh * LL * HD;
  const unsigned short* Kp = Klmb + (size_t)bh * NL * HD;
  const unsigned short* Wp = w2t + (size_t)bh * HD * NL;

  for (int i = t; i < NL * HD / 4; i += 256) {
    int flat = i * 4, rr = flat >> 6, dd = flat & 63;
    *(uint2*)&klm_s[rr * KSD + dd] = *(const uint2*)&Kp[flat];
  }
  __syncthreads();

  f32x4 sacc[2][8];
#pragma unroll
  for (int i = 0; i < 2; i++)
#pragma unroll
    for (int j = 0; j < 8; j++) sacc[i][j] = f32x4{0.f, 0.f, 0.f, 0.f};
#pragma unroll
  for (int kc = 0; kc < 2; kc++) {
    bf16x8 aq[2];
#pragma unroll
    for (int i = 0; i < 2; i++)
      aq[i] = *(const bf16x8*)&Qp[(size_t)(l0 + wm + i * 16 + lane16) * HD + kc * 32 + lgrp * 8];
#pragma unroll
    for (int j = 0; j < 8; j++) {
      bf16x8 bk = *(const bf16x8*)&klm_s[(j * 16 + lane16) * KSD + kc * 32 + lgrp * 8];
#pragma unroll
      for (int i = 0; i < 2; i++) sacc[i][j] = mfma16(aq[i], bk, sacc[i][j]);
    }
  }

#pragma unroll
  for (int i = 0; i < 2; i++) {
#pragma unroll
    for (int r = 0; r < 4; r++) {
      float mx = -1e30f;
#pragma unroll
      for (int j = 0; j < 8; j++) mx = fmaxf(mx, sacc[i][j][r]);
      mx = fmaxf(mx, __shfl_xor(mx, 1, 16));
      mx = fmaxf(mx, __shfl_xor(mx, 2, 16));
      mx = fmaxf(mx, __shfl_xor(mx, 4, 16));
      mx = fmaxf(mx, __shfl_xor(mx, 8, 16));
      float sum = 0.f;
#pragma unroll
      for (int j = 0; j < 8; j++) {
        float e = __expf(sacc[i][j][r] - mx);
        sacc[i][j][r] = e;
        sum += e;
      }
      sum += __shfl_xor(sum, 1, 16);
      sum += __shfl_xor(sum, 2, 16);
      sum += __shfl_xor(sum, 4, 16);
      sum += __shfl_xor(sum, 8, 16);
      float inv = 1.0f / fmaxf(sum, 1e-30f);
      int row = wm + i * 16 + lgrp * 4 + r;
#pragma unroll
      for (int j = 0; j < 8; j++)
        p_s[row * PSD + j * 16 + lane16] = f2bf(sacc[i][j][r] * inv);
    }
  }
  __syncthreads();

  f32x4 oacc[2][4];
#pragma unroll
  for (int i = 0; i < 2; i++)
#pragma unroll
    for (int j = 0; j < 4; j++) oacc[i][j] = f32x4{0.f, 0.f, 0.f, 0.f};
#pragma unroll
  for (int kc = 0; kc < 4; kc++) {
    bf16x8 ap[2];
#pragma unroll
    for (int i = 0; i < 2; i++)
      ap[i] = *(const bf16x8*)&p_s[(wm + i * 16 + lane16) * PSD + kc * 32 + lgrp * 8];
#pragma unroll
    for (int j = 0; j < 4; j++) {
      bf16x8 bw = *(const bf16x8*)&Wp[(size_t)(j * 16 + lane16) * NL + kc * 32 + lgrp * 8];
#pragma unroll
      for (int i = 0; i < 2; i++) oacc[i][j] = mfma16(ap[i], bw, oacc[i][j]);
    }
  }

  const int b = bh >> 4, h = bh & 15;
#pragma unroll
  for (int i = 0; i < 2; i++)
#pragma unroll
    for (int j = 0; j < 4; j++)
#pragma unroll
      for (int r = 0; r < 4; r++) {
        int row = wm + i * 16 + lgrp * 4 + r;
        int dd = j * 16 + lane16;
        outp[((size_t)b * LL + l0 + row) * DM + h * HD + dd] = oacc[i][j][r];  // FP32 store
      }
}

// ---------------------------------------------------------------------------
extern "C" void kernel_launch(void* const* d_in, const int* in_sizes, int n_in,
                              void* d_out, int out_size, void* d_ws, size_t ws_size,
                              hipStream_t stream) {
  (void)in_sizes; (void)n_in; (void)out_size; (void)ws_size;
  float* outp = (float*)d_out;  // reference output dtype = float32

  char* ws = (char*)d_ws;
  size_t off = 0;
  auto alloc = [&](size_t bytes) -> void* {
    void* p = ws + off;
    off += (bytes + 255) & ~(size_t)255;
    return p;
  };
  int* flags = (int*)alloc(64);
  unsigned* alpha_bits = (unsigned*)alloc(64);
  float* colsum_g = (float*)alloc((size_t)BH * NL * 4);
  float* Qlm = (float*)alloc((size_t)BH * NL * HD * 4);
  float* Klm = (float*)alloc((size_t)BH * NL * HD * 4);
  unsigned short* Qlmb = (unsigned short*)alloc((size_t)BH * NL * HD * 2);
  unsigned short* Klmb = (unsigned short*)alloc((size_t)BH * NL * HD * 2);
  float* k2 = (float*)alloc((size_t)BH * NL * NL * 4);
  unsigned short* w2t = (unsigned short*)alloc((size_t)BH * HD * NL * 2);
  unsigned short* Wb = (unsigned short*)alloc((size_t)3 * DM * DM * 2);
  float* bb = (float*)alloc((size_t)3 * DM * 4);
  // union region: xb (bf16 x, 33.6 MB — dead after proj) aliases the k3v
  // split-K partials op/mp/lp (34.6 MB at NSPLIT=16 — written after proj).
  const size_t OP_BYTES = (size_t)BH * NSPLIT * NL * HD * 4;           // 33.55 MB
  const size_t ML_BYTES = (size_t)BH * NSPLIT * NL * 4;                // 0.5 MB
  const size_t XB_BYTES = (size_t)4 * LL * DM * 2;                     // 33.55 MB
  const size_t UB_BYTES = OP_BYTES + 2 * ML_BYTES + 512;
  char* ub = (char*)alloc(UB_BYTES > XB_BYTES ? UB_BYTES : XB_BYTES);
  unsigned short* xb = (unsigned short*)ub;
  float* op = (float*)ub;
  float* mp = (float*)(ub + OP_BYTES);
  float* lp = mp + (size_t)BH * NSPLIT * NL;
  const size_t QKV = (size_t)BH * LL * HD;
  unsigned short* Qb = (unsigned short*)alloc(QKV * 2);
  unsigned short* Kb = (unsigned short*)alloc(QKV * 2);
  unsigned short* Vb = (unsigned short*)alloc(QKV * 2);

  hipMemsetAsync(colsum_g, 0, (size_t)BH * NL * 4, stream);
  probe_kernel<<<7, 256, 0, stream>>>(
      (const unsigned short*)d_in[0], (const unsigned short*)d_in[1],
      (const unsigned short*)d_in[2], (const unsigned short*)d_in[3],
      (const unsigned short*)d_in[4], (const unsigned short*)d_in[5],
      (const unsigned short*)d_in[6], flags);
  cvtx_kernel<<<2048, 256, 0, stream>>>(d_in[0], flags, 0, xb, 4 * LL * DM / 8);
  cvtw_kernel<<<1537, 256, 0, stream>>>(
      d_in[1], d_in[3], d_in[5], d_in[2], d_in[4], d_in[6], flags, Wb, bb);
  proj_kernel<<<128 * 24, 256, 0, stream>>>(xb, Wb, bb, Qb, Kb, Vb,
                                            Qlm, Klm, Qlmb, Klmb);
  k2_kernel<<<BH * 8, 256, 0, stream>>>(Qlm, Klm, k2, colsum_g);
  alpha_kernel<<<1, 256, 0, stream>>>(colsum_g, alpha_bits);
  k3v_kernel<<<BH * NSPLIT, 256, 0, stream>>>(Qlmb, Kb, Vb, op, mp, lp);
  ns_kernel<<<BH, 512, 0, stream>>>(k2, alpha_bits, op, mp, lp, w2t);
  final_kernel<<<BH * 32, 256, 0, stream>>>(Qb, Klmb, w2t, outp);
}

// Round 10
// 466.356 us; speedup vs baseline: 1.0319x; 1.0319x over previous
//
#include <hip/hip_runtime.h>
#include <hip/hip_bf16.h>
#include <stdint.h>

#define DEV __device__ __forceinline__

typedef __attribute__((ext_vector_type(8))) short bf16x8;
typedef __attribute__((ext_vector_type(4))) short short4v;
typedef __attribute__((ext_vector_type(4))) float f32x4;

static constexpr int LL = 4096;
static constexpr int NH = 16;
static constexpr int HD = 64;
static constexpr int DM = 1024;
static constexpr int NL = 128;    // landmarks
static constexpr int BH = 64;     // B*NH
static constexpr int NSPLIT = 16; // split-K factor for k3v flash
static constexpr float QK_SCALE = 0.35355339059327379f;  // 1/sqrt(sqrt(64))

DEV short f2bf(float f) {
  union { __hip_bfloat16 h; short s; } u;
  u.h = __float2bfloat16(f);
  return u.s;
}
DEV float bf2f(unsigned short s) {
  union { unsigned u; float f; } u;
  u.u = ((unsigned)s) << 16;
  return u.f;
}
DEV float clampf(float v) {  // also scrubs NaN (AMD IEEE min/max return the non-NaN operand)
  return fminf(fmaxf(v, -1e6f), 1e6f);
}

DEV f32x4 mfma16(bf16x8 a, bf16x8 b, f32x4 c) {
  return __builtin_amdgcn_mfma_f32_16x16x32_bf16(a, b, c, 0, 0, 0);
}

DEV void gl2lds16(const void* g, void* l) {
  __builtin_amdgcn_global_load_lds(
      (const __attribute__((address_space(1))) void*)g,
      (__attribute__((address_space(3))) void*)l, 16, 0, 0);
}

// hi/lo bf16 split of one fp32 value (truncate-to-bf16 hi, rounded residual lo)
DEV void split1(float f, short& hi, short& lo) {
  unsigned u = __float_as_uint(f);
  hi = (short)(u >> 16);
  lo = f2bf(f - __uint_as_float(u & 0xffff0000u));
}

// split 8 fp32 values into hi/lo bf16x8 vectors
DEV void split8(const float* av, bf16x8& hv, bf16x8& lv) {
#pragma unroll
  for (int e = 0; e < 8; e++) {
    short hi, lo;
    split1(av[e], hi, lo);
    hv[e] = hi;
    lv[e] = lo;
  }
}

// ---------------------------------------------------------------------------
// Kernel 0: dtype probe.  flags[i]=1 if input i looks like fp32.
// ---------------------------------------------------------------------------
__global__ __launch_bounds__(256) void probe_kernel(
    const unsigned short* p0, const unsigned short* p1, const unsigned short* p2,
    const unsigned short* p3, const unsigned short* p4, const unsigned short* p5,
    const unsigned short* p6, int* flags)
{
  const unsigned short* ps[7] = {p0, p1, p2, p3, p4, p5, p6};
  const unsigned short* p = ps[blockIdx.x];
  const int t = threadIdx.x;
  __shared__ int cnt;
  if (t == 0) cnt = 0;
  __syncthreads();
  int c = 0;
  for (int i = t; i < 512; i += 256) {
    unsigned e = (p[2 * i] >> 7) & 0xFF;
    if (e > 90 && e < 160) c++;
  }
  atomicAdd(&cnt, c);
  __syncthreads();
  if (t == 0) flags[blockIdx.x] = (cnt < 358) ? 1 : 0;  // <70% sane => fp32
}

// ---------------------------------------------------------------------------
// Kernel 0b: convert x to bf16 (or copy if already bf16).  n8 = elems/8.
// ---------------------------------------------------------------------------
__global__ __launch_bounds__(256) void cvtx_kernel(
    const void* __restrict__ src, const int* __restrict__ flags, int fidx,
    unsigned short* __restrict__ dst, int n8)
{
  const int f32 = flags[fidx];
  for (int i = blockIdx.x * 256 + threadIdx.x; i < n8; i += gridDim.x * 256) {
    if (f32) {
      const float* s = (const float*)src + (size_t)i * 8;
      f32x4 a = *(const f32x4*)s;
      f32x4 b = *(const f32x4*)(s + 4);
      bf16x8 o;
      o[0] = f2bf(a[0]); o[1] = f2bf(a[1]); o[2] = f2bf(a[2]); o[3] = f2bf(a[3]);
      o[4] = f2bf(b[0]); o[5] = f2bf(b[1]); o[6] = f2bf(b[2]); o[7] = f2bf(b[3]);
      *(bf16x8*)(dst + (size_t)i * 8) = o;
    } else {
      *(bf16x8*)(dst + (size_t)i * 8) =
          *(const bf16x8*)((const unsigned short*)src + (size_t)i * 8);
    }
  }
}

// ---------------------------------------------------------------------------
// Kernel 0c: convert Wq/Wk/Wv -> packed bf16 Wb[3][1024][1024], biases -> fp32.
// ---------------------------------------------------------------------------
__global__ __launch_bounds__(256) void cvtw_kernel(
    const void* __restrict__ Wq, const void* __restrict__ Wk, const void* __restrict__ Wv,
    const void* __restrict__ bq, const void* __restrict__ bk, const void* __restrict__ bv,
    const int* __restrict__ flags,
    unsigned short* __restrict__ Wb, float* __restrict__ bb)
{
  const int bid = blockIdx.x, t = threadIdx.x;
  if (bid < 1536) {
    const int q = bid / 512;
    const int i = (bid % 512) * 256 + t;     // elem8 index within one W
    const void* src = (q == 0) ? Wq : ((q == 1) ? Wk : Wv);
    unsigned short* dst = Wb + (size_t)q * DM * DM;
    if (flags[1 + 2 * q]) {
      const float* s = (const float*)src + (size_t)i * 8;
      f32x4 a = *(const f32x4*)s;
      f32x4 b = *(const f32x4*)(s + 4);
      bf16x8 o;
      o[0] = f2bf(a[0]); o[1] = f2bf(a[1]); o[2] = f2bf(a[2]); o[3] = f2bf(a[3]);
      o[4] = f2bf(b[0]); o[5] = f2bf(b[1]); o[6] = f2bf(b[2]); o[7] = f2bf(b[3]);
      *(bf16x8*)(dst + (size_t)i * 8) = o;
    } else {
      *(bf16x8*)(dst + (size_t)i * 8) =
          *(const bf16x8*)((const unsigned short*)src + (size_t)i * 8);
    }
  } else {
    for (int i = t; i < 3 * DM; i += 256) {
      int q = i >> 10, idx = i & 1023;
      const void* src = (q == 0) ? bq : ((q == 1) ? bk : bv);
      bb[i] = flags[2 + 2 * q] ? ((const float*)src)[idx]
                               : bf2f(((const unsigned short*)src)[idx]);
    }
  }
}

// ---------------------------------------------------------------------------
// Kernel 1 (BK=64, two-panel LDS): one output (Q|K|V) x one 128-col tile per
// block.  Landmark means written in BOTH fp32 (k2) and bf16 (k3v/final).
// ---------------------------------------------------------------------------
__global__ __launch_bounds__(256, 2) void proj_kernel(
    const unsigned short* __restrict__ xb,
    const unsigned short* __restrict__ Wb,
    const float* __restrict__ bb,
    unsigned short* __restrict__ Qo, unsigned short* __restrict__ Ko,
    unsigned short* __restrict__ Vo,
    float* __restrict__ Qlm, float* __restrict__ Klm,
    unsigned short* __restrict__ Qlmb, unsigned short* __restrict__ Klmb)
{
  __shared__ __align__(16) short As[2][128 * 32];
  __shared__ __align__(16) short Bs[2][128 * 32];

  const int t = threadIdx.x;
  const int w = t >> 6;
  const int l = t & 63;
  const int lane16 = l & 15, lgrp = l >> 4;

  const int bid = blockIdx.x;
  const int mt = bid & 127;
  const int nt = bid >> 7;
  const int which = nt >> 3;  // 0=Q 1=K 2=V
  const int m0 = mt * 128;
  const int ncol0 = (nt & 7) * 128;

  unsigned short* outp = (which == 0) ? Qo : ((which == 1) ? Ko : Vo);
  const float scl = (which == 2) ? 1.0f : QK_SCALE;

  const int srow = w * 16 + (l >> 2);
  const int skc = (l & 3) * 8;
  const unsigned short* gA = xb + (size_t)(m0 + srow) * DM + skc;
  const unsigned short* gB = Wb + (size_t)which * DM * DM + (size_t)(ncol0 + srow) * DM + skc;
  short* lA0 = As[0] + w * 512;  // wave-uniform base for gl2lds (HW adds lane*16B)
  short* lA1 = As[1] + w * 512;
  short* lB0 = Bs[0] + w * 512;
  short* lB1 = Bs[1] + w * 512;

  const int wm = (w >> 1) * 64;
  const int wn = (w & 1) * 64;

  f32x4 acc[4][4];
#pragma unroll
  for (int i = 0; i < 4; i++)
#pragma unroll
    for (int j = 0; j < 4; j++) acc[i][j] = f32x4{0.f, 0.f, 0.f, 0.f};

  for (int kk = 0; kk < DM; kk += 64) {
    gl2lds16(gA + kk, lA0);
    gl2lds16(gA + kk + 64 * DM, lA0 + 2048);
    gl2lds16(gA + kk + 32, lA1);
    gl2lds16(gA + kk + 32 + 64 * DM, lA1 + 2048);
    gl2lds16(gB + kk, lB0);
    gl2lds16(gB + kk + 64 * DM, lB0 + 2048);
    gl2lds16(gB + kk + 32, lB1);
    gl2lds16(gB + kk + 32 + 64 * DM, lB1 + 2048);
    __syncthreads();
#pragma unroll
    for (int kc = 0; kc < 2; kc++) {
      bf16x8 af[4], bfv[4];
#pragma unroll
      for (int i = 0; i < 4; i++) {
        af[i]  = *(const bf16x8*)&As[kc][(wm + i * 16 + lane16) * 32 + lgrp * 8];
        bfv[i] = *(const bf16x8*)&Bs[kc][(wn + i * 16 + lane16) * 32 + lgrp * 8];
      }
#pragma unroll
      for (int i = 0; i < 4; i++)
#pragma unroll
        for (int j = 0; j < 4; j++)
          acc[i][j] = mfma16(af[i], bfv[j], acc[i][j]);
    }
    __syncthreads();
  }

  const int b = m0 >> 12;
  const int hh = (ncol0 + wn) >> 6;
  float bv4[4];
#pragma unroll
  for (int j = 0; j < 4; j++)
    bv4[j] = bb[which * DM + ncol0 + wn + j * 16 + lane16];

  float seg[2][4];
#pragma unroll
  for (int s = 0; s < 2; s++)
#pragma unroll
    for (int j = 0; j < 4; j++) seg[s][j] = 0.f;

#pragma unroll
  for (int i = 0; i < 4; i++) {
#pragma unroll
    for (int j = 0; j < 4; j++) {
#pragma unroll
      for (int r = 0; r < 4; r++) {
        float v = (acc[i][j][r] + bv4[j]) * scl;
        int row = wm + i * 16 + lgrp * 4 + r;
        int li = (m0 + row) & 4095;
        int dd = (wn + j * 16 + lane16) & 63;
        outp[(((size_t)(b * NH + hh)) * LL + li) * HD + dd] = (unsigned short)f2bf(v);
        seg[i >> 1][j] += v;
      }
    }
  }
  if (which < 2) {
    float* lmb = (which == 0) ? Qlm : Klm;
    unsigned short* lmbb = (which == 0) ? Qlmb : Klmb;
#pragma unroll
    for (int s = 0; s < 2; s++) {
#pragma unroll
      for (int j = 0; j < 4; j++) {
        float ssum = seg[s][j];
        ssum += __shfl_xor(ssum, 16, 64);
        ssum += __shfl_xor(ssum, 32, 64);
        if (lgrp == 0) {
          int m = ((m0 + wm + s * 32) & 4095) >> 5;
          int dd = (wn + j * 16 + lane16) & 63;
          float mv = clampf(ssum * (1.0f / 32.0f));
          size_t idx = (((size_t)(b * NH + hh)) * NL + m) * HD + dd;
          lmb[idx] = mv;
          lmbb[idx] = (unsigned short)f2bf(mv);
        }
      }
    }
  }
}

// ---------------------------------------------------------------------------
// Kernel 3: kernel_2 = softmax(Qlm @ Klm^T) fp32, re-partitioned (512 blocks,
// dots cached in registers).  Partial colsums -> global via atomicAdd.
// ---------------------------------------------------------------------------
__global__ __launch_bounds__(256, 1) void k2_kernel(
    const float* __restrict__ Qlm, const float* __restrict__ Klm,
    float* __restrict__ k2, float* __restrict__ colsum_g)
{
  __shared__ float cs[NL];
  const int bid = blockIdx.x;
  const int bh = bid >> 3;
  const int rc = bid & 7;            // 16-row chunk
  const int t = threadIdx.x;
  const int r = t >> 4;              // local row 0..15
  const int c = t & 15;              // col lane 0..15
  const int row = rc * 16 + r;
  const float* Q = Qlm + ((size_t)bh * NL + row) * HD;
  const float* K = Klm + (size_t)bh * NL * HD;
  float* k2p = k2 + (size_t)bh * NL * NL;

  for (int i = t; i < NL; i += 256) cs[i] = 0.f;

  f32x4 q4[16];
#pragma unroll
  for (int d = 0; d < 16; d++) q4[d] = *(const f32x4*)&Q[d * 4];

  float dots[8];
#pragma unroll
  for (int g = 0; g < 8; g++) {
    const float* kr = K + (size_t)(c + g * 16) * HD;
    float s = 0.f;
#pragma unroll
    for (int d = 0; d < 16; d++) {
      f32x4 k4 = *(const f32x4*)&kr[d * 4];
      s += q4[d][0] * k4[0];
      s += q4[d][1] * k4[1];
      s += q4[d][2] * k4[2];
      s += q4[d][3] * k4[3];
    }
    dots[g] = s;
  }

  float mx = dots[0];
#pragma unroll
  for (int g = 1; g < 8; g++) mx = fmaxf(mx, dots[g]);
  mx = fmaxf(mx, __shfl_xor(mx, 1, 16));
  mx = fmaxf(mx, __shfl_xor(mx, 2, 16));
  mx = fmaxf(mx, __shfl_xor(mx, 4, 16));
  mx = fmaxf(mx, __shfl_xor(mx, 8, 16));

  float sum = 0.f;
#pragma unroll
  for (int g = 0; g < 8; g++) {
    float e = __expf(dots[g] - mx);
    dots[g] = e;
    sum += e;
  }
  sum += __shfl_xor(sum, 1, 16);
  sum += __shfl_xor(sum, 2, 16);
  sum += __shfl_xor(sum, 4, 16);
  sum += __shfl_xor(sum, 8, 16);
  const float inv = 1.0f / fmaxf(sum, 1e-30f);

  __syncthreads();  // cs init complete
#pragma unroll
  for (int g = 0; g < 8; g++) {
    float p = dots[g] * inv;
    k2p[(size_t)row * NL + c + g * 16] = p;
    atomicAdd(&cs[c + g * 16], p);
  }
  __syncthreads();
  for (int i = t; i < NL; i += 256) atomicAdd(&colsum_g[bh * NL + i], cs[i]);
}

// ---------------------------------------------------------------------------
// Kernel 3b: alpha = max over all (bh, col) colsums.  Single block.
// ---------------------------------------------------------------------------
__global__ __launch_bounds__(256) void alpha_kernel(
    const float* __restrict__ colsum_g, unsigned* __restrict__ alpha_bits)
{
  __shared__ float wm[4];
  const int t = threadIdx.x;
  float m = 0.f;  // colsums are sums of softmax probs >= 0
  for (int i = t; i < BH * NL; i += 256) m = fmaxf(m, colsum_g[i]);
#pragma unroll
  for (int o = 1; o < 64; o <<= 1) m = fmaxf(m, __shfl_xor(m, o, 64));
  if ((t & 63) == 0) wm[t >> 6] = m;
  __syncthreads();
  if (t == 0)
    *alpha_bits = __float_as_uint(fmaxf(fmaxf(wm[0], wm[1]), fmaxf(wm[2], wm[3])));
}

// ---------------------------------------------------------------------------
// Kernel 4 (SPLIT-K, NSPLIT=16): partial flash over L-range [sp*256, +256).
// ---------------------------------------------------------------------------
__global__ __launch_bounds__(256, 1) void k3v_kernel(
    const unsigned short* __restrict__ Qlmb, const unsigned short* __restrict__ K,
    const unsigned short* __restrict__ V,
    float* __restrict__ op, float* __restrict__ mp, float* __restrict__ lp)
{
  constexpr int LT = 64;
  constexpr int ST = 72;
  __shared__ __align__(16) short q_s[NL * ST];
  __shared__ __align__(16) short k_s[LT * ST];
  __shared__ __align__(16) short vt_s[HD * ST];
  __shared__ __align__(16) short p_s[NL * ST];

  const int bid = blockIdx.x;
  const int bh = bid >> 4;           // NSPLIT = 16
  const int sp = bid & (NSPLIT - 1);
  const int t = threadIdx.x;
  const int w = t >> 6, l = t & 63;
  const int lane16 = l & 15, lgrp = l >> 4;
  const int wm = w * 32;
  const unsigned short* Kp = K + (size_t)bh * LL * HD;
  const unsigned short* Vp = V + (size_t)bh * LL * HD;

  for (int i = t; i < NL * HD / 4; i += 256) {
    int flat = i * 4, rr = flat >> 6, dd = flat & 63;
    *(uint2*)&q_s[rr * ST + dd] = *(const uint2*)&Qlmb[(size_t)bh * NL * HD + flat];
  }

  f32x4 oacc[2][4];
  float mrun[2][4], lrun[2][4];
#pragma unroll
  for (int i = 0; i < 2; i++)
#pragma unroll
    for (int j = 0; j < 4; j++) oacc[i][j] = f32x4{0.f, 0.f, 0.f, 0.f};
#pragma unroll
  for (int i = 0; i < 2; i++)
#pragma unroll
    for (int r = 0; r < 4; r++) { mrun[i][r] = -3.0e38f; lrun[i][r] = 0.f; }

  constexpr int TPS = LL / LT / NSPLIT;  // tiles per split = 4
  for (int lt = sp * TPS; lt < (sp + 1) * TPS; lt++) {
    const int l0 = lt * LT;
    for (int i = t; i < LT * HD / 4; i += 256) {
      int flat = i * 4, rr = flat >> 6, dd = flat & 63;
      *(uint2*)&k_s[rr * ST + dd] = *(const uint2*)&Kp[(size_t)(l0 + rr) * HD + dd];
      uint2 raw = *(const uint2*)&Vp[(size_t)(l0 + rr) * HD + dd];
      vt_s[(dd + 0) * ST + rr] = (short)(raw.x & 0xffff);
      vt_s[(dd + 1) * ST + rr] = (short)(raw.x >> 16);
      vt_s[(dd + 2) * ST + rr] = (short)(raw.y & 0xffff);
      vt_s[(dd + 3) * ST + rr] = (short)(raw.y >> 16);
    }
    __syncthreads();

    f32x4 sacc[2][4];
#pragma unroll
    for (int i = 0; i < 2; i++)
#pragma unroll
      for (int j = 0; j < 4; j++) sacc[i][j] = f32x4{0.f, 0.f, 0.f, 0.f};
#pragma unroll
    for (int kc = 0; kc < 2; kc++) {
      bf16x8 aq[2];
#pragma unroll
      for (int i = 0; i < 2; i++)
        aq[i] = *(const bf16x8*)&q_s[(wm + i * 16 + lane16) * ST + kc * 32 + lgrp * 8];
#pragma unroll
      for (int j = 0; j < 4; j++) {
        bf16x8 bk = *(const bf16x8*)&k_s[(j * 16 + lane16) * ST + kc * 32 + lgrp * 8];
#pragma unroll
        for (int i = 0; i < 2; i++) sacc[i][j] = mfma16(aq[i], bk, sacc[i][j]);
      }
    }

#pragma unroll
    for (int i = 0; i < 2; i++) {
#pragma unroll
      for (int r = 0; r < 4; r++) {
        float tm = fmaxf(fmaxf(sacc[i][0][r], sacc[i][1][r]),
                         fmaxf(sacc[i][2][r], sacc[i][3][r]));
        tm = fmaxf(tm, __shfl_xor(tm, 1, 16));
        tm = fmaxf(tm, __shfl_xor(tm, 2, 16));
        tm = fmaxf(tm, __shfl_xor(tm, 4, 16));
        tm = fmaxf(tm, __shfl_xor(tm, 8, 16));
        float mnew = fmaxf(mrun[i][r], tm);
        float al = __expf(mrun[i][r] - mnew);
        float rs = 0.f;
#pragma unroll
        for (int j = 0; j < 4; j++) {
          float e = __expf(sacc[i][j][r] - mnew);
          sacc[i][j][r] = e;
          rs += e;
        }
        rs += __shfl_xor(rs, 1, 16);
        rs += __shfl_xor(rs, 2, 16);
        rs += __shfl_xor(rs, 4, 16);
        rs += __shfl_xor(rs, 8, 16);
        lrun[i][r] = lrun[i][r] * al + rs;
        mrun[i][r] = mnew;
#pragma unroll
        for (int j = 0; j < 4; j++) oacc[i][j][r] *= al;
        int row = wm + i * 16 + lgrp * 4 + r;
#pragma unroll
        for (int j = 0; j < 4; j++)
          p_s[row * ST + j * 16 + lane16] = f2bf(sacc[i][j][r]);
      }
    }
    __syncthreads();

#pragma unroll
    for (int kc = 0; kc < 2; kc++) {
      bf16x8 ap[2];
#pragma unroll
      for (int i = 0; i < 2; i++)
        ap[i] = *(const bf16x8*)&p_s[(wm + i * 16 + lane16) * ST + kc * 32 + lgrp * 8];
#pragma unroll
      for (int j = 0; j < 4; j++) {
        bf16x8 bv = *(const bf16x8*)&vt_s[(j * 16 + lane16) * ST + kc * 32 + lgrp * 8];
#pragma unroll
        for (int i = 0; i < 2; i++) oacc[i][j] = mfma16(ap[i], bv, oacc[i][j]);
      }
    }
    __syncthreads();
  }

  // unnormalized partial out + per-row m,l
  float* opp = op + ((size_t)(bh * NSPLIT + sp)) * NL * HD;
#pragma unroll
  for (int i = 0; i < 2; i++)
#pragma unroll
    for (int j = 0; j < 4; j++)
#pragma unroll
      for (int r = 0; r < 4; r++) {
        int row = wm + i * 16 + lgrp * 4 + r;
        int dd = j * 16 + lane16;
        opp[(size_t)row * HD + dd] = oacc[i][j][r];
      }
  if (lane16 == 0) {
    const size_t base = (size_t)(bh * NSPLIT + sp) * NL;
#pragma unroll
    for (int i = 0; i < 2; i++)
#pragma unroll
      for (int r = 0; r < 4; r++) {
        int row = wm + i * 16 + lgrp * 4 + r;
        mp[base + row] = mrun[i][r];
        lp[base + row] = lrun[i][r];
      }
  }
}

// ---------------------------------------------------------------------------
// Kernel 4b: combine NSPLIT flash partials -> k3v fp32 (2048 blocks — the
// high-occupancy read of the 33.5 MB partials; round 9 folded this into the
// 64-block ns kernel and lost ~40 us to the low-occupancy read).
// ---------------------------------------------------------------------------
__global__ __launch_bounds__(256) void k3v_combine(
    const float* __restrict__ op, const float* __restrict__ mp,
    const float* __restrict__ lp, float* __restrict__ k3v)
{
  const int idx = blockIdx.x * 256 + threadIdx.x;  // over BH*NL*HD
  const int dd = idx & 63;
  const int row = (idx >> 6) & 127;
  const int bh = idx >> 13;
  (void)dd;
  float m = -3.0e38f;
  float ms[NSPLIT];
#pragma unroll
  for (int s = 0; s < NSPLIT; s++) {
    ms[s] = mp[(size_t)(bh * NSPLIT + s) * NL + row];
    m = fmaxf(m, ms[s]);
  }
  float o = 0.f, ltot = 0.f;
#pragma unroll
  for (int s = 0; s < NSPLIT; s++) {
    float sc = __expf(ms[s] - m);
    ltot += lp[(size_t)(bh * NSPLIT + s) * NL + row] * sc;
    o += op[((size_t)(bh * NSPLIT + s) * NL + row) * HD + dd] * sc;
  }
  k3v[idx] = clampf(o / fmaxf(ltot, 1e-30f));
}

// ---------------------------------------------------------------------------
// Kernel 5: Newton-Schulz pseudo-inverse, 6 iterations, hi/lo-split bf16 MFMA,
// fully LDS-resident (8-barrier/iter form — the proven register-friendly
// structure).  Tail: W2 = Vinv @ k3v (reads the 2 MB combined k3v).
// ---------------------------------------------------------------------------
__global__ __launch_bounds__(512, 1) void ns_kernel(
    const float* __restrict__ k2, const unsigned* __restrict__ alpha_bits,
    const float* __restrict__ k3v, unsigned short* __restrict__ w2t)
{
  constexpr int VST = 132;   // fp32 row stride: 132 mod 32 = 4 -> 2-way (free) banks
  constexpr int BST = 136;   // bf16 row stride: 68 dwords -> uniform b128 starts
  __shared__ __align__(16) float Vf[NL * VST];    // 67.6 KB
  __shared__ __align__(16) short Bth[NL * BST];   // 34.8 KB
  __shared__ __align__(16) short Btl[NL * BST];   // 34.8 KB  (total 137 KB < 160 KB)

  const int bh = blockIdx.x, t = threadIdx.x;
  const int w = t >> 6, l = t & 63;
  const int lane16 = l & 15, lgrp = l >> 4;
  const float* K2 = k2 + (size_t)bh * NL * NL;

  // --- K2 A-fragments (hi/lo) into registers, once (64 VGPRs) ---
  bf16x8 k2hi[4], k2lo[4];
#pragma unroll
  for (int kk = 0; kk < 4; kk++) {
    const float* ap = K2 + (size_t)(w * 16 + lane16) * NL + kk * 32 + lgrp * 8;
    f32x4 a0 = *(const f32x4*)ap;
    f32x4 a1 = *(const f32x4*)(ap + 4);
    float av[8] = {a0[0], a0[1], a0[2], a0[3], a1[0], a1[1], a1[2], a1[3]};
    split8(av, k2hi[kk], k2lo[kk]);
  }

  // --- init: V = clamp(K2^T * inva) -> Vf row-major; Bt = V^T = clamp(K2*inva)
  const float inva = 1.0f / fmaxf(__uint_as_float(*alpha_bits), 1e-30f);
  for (int i = t; i < NL * NL; i += 512) {
    int rr = i >> 7, cc = i & 127;
    float v = clampf(K2[(size_t)cc * NL + rr] * inva);
    Vf[rr * VST + cc] = v;
    short hi, lo; split1(v, hi, lo);
    Bth[cc * BST + rr] = hi;
    Btl[cc * BST + rr] = lo;
  }
  __syncthreads();

  f32x4 macc[8], vacc[8];

  // macc = A @ B  with A-fragments in registers, B = Bt (transposed hi/lo)
  auto mmA = [&](const bf16x8* ahi, const bf16x8* alo) {
#pragma unroll
    for (int j = 0; j < 8; j++) macc[j] = f32x4{0.f, 0.f, 0.f, 0.f};
#pragma unroll
    for (int kk = 0; kk < 4; kk++) {
#pragma unroll
      for (int j = 0; j < 8; j++) {
        const int bo = (j * 16 + lane16) * BST + kk * 32 + lgrp * 8;
        bf16x8 bh_ = *(const bf16x8*)&Bth[bo];
        bf16x8 bl_ = *(const bf16x8*)&Btl[bo];
        macc[j] = mfma16(alo[kk], bh_, macc[j]);
        macc[j] = mfma16(ahi[kk], bl_, macc[j]);
        macc[j] = mfma16(ahi[kk], bh_, macc[j]);
      }
    }
  };

  // macc = Vf @ B (A rows = this wave's 16 rows of Vf, split on the fly)
  auto mmV = [&]() {
    bf16x8 ahi[4], alo[4];
#pragma unroll
    for (int kk = 0; kk < 4; kk++) {
      const float* ap = &Vf[(w * 16 + lane16) * VST + kk * 32 + lgrp * 8];
      f32x4 a0 = *(const f32x4*)ap;
      f32x4 a1 = *(const f32x4*)(ap + 4);
      float av[8] = {a0[0], a0[1], a0[2], a0[3], a1[0], a1[1], a1[2], a1[3]};
      split8(av, ahi[kk], alo[kk]);
    }
    mmA(ahi, alo);
  };

  // Bt <- clamp(macc)^T  (packed b64 writes: 4 consecutive rows per lane)
  auto writeBt = [&]() {
#pragma unroll
    for (int j = 0; j < 8; j++) {
      short4v hv, lv;
#pragma unroll
      for (int r = 0; r < 4; r++) {
        float c = clampf(macc[j][r]);
        short hi, lo; split1(c, hi, lo);
        hv[r] = hi; lv[r] = lo;
      }
      const int base = (j * 16 + lane16) * BST + w * 16 + lgrp * 4;
      *(short4v*)&Bth[base] = hv;
      *(short4v*)&Btl[base] = lv;
    }
  };

  for (int it = 0; it < 6; it++) {
    // KV = K2 @ V   (B = Bt holding V^T)
    mmA(k2hi, k2lo);
    __syncthreads();              // all waves done reading Bt(V^T)
    writeBt();                    // Bt <- KV^T (clamped), B for mm2..mm4
    __syncthreads();

    // M1 = V @ KV ; vacc = 3.25*V - 3.75*M1
    mmV();
#pragma unroll
    for (int j = 0; j < 8; j++)
#pragma unroll
      for (int r = 0; r < 4; r++)
        vacc[j][r] = 3.25f * Vf[(w * 16 + lgrp * 4 + r) * VST + j * 16 + lane16]
                   - 3.75f * macc[j][r];
    __syncthreads();
#pragma unroll
    for (int j = 0; j < 8; j++)
#pragma unroll
      for (int r = 0; r < 4; r++)
        Vf[(w * 16 + lgrp * 4 + r) * VST + j * 16 + lane16] = clampf(macc[j][r]);
    __syncthreads();

    // M2 = M1 @ KV ; vacc += 1.75*M2
    mmV();
#pragma unroll
    for (int j = 0; j < 8; j++)
#pragma unroll
      for (int r = 0; r < 4; r++) vacc[j][r] += 1.75f * macc[j][r];
    __syncthreads();
#pragma unroll
    for (int j = 0; j < 8; j++)
#pragma unroll
      for (int r = 0; r < 4; r++)
        Vf[(w * 16 + lgrp * 4 + r) * VST + j * 16 + lane16] = clampf(macc[j][r]);
    __syncthreads();

    // M3 = M2 @ KV ; V_new = clamp(vacc - 0.25*M3) -> Vf + Bt (for next iter)
    mmV();
    __syncthreads();              // all waves done reading Bt(KV^T) + Vf(M2)
#pragma unroll
    for (int j = 0; j < 8; j++) {
      short4v hv, lv;
#pragma unroll
      for (int r = 0; r < 4; r++) {
        float v = clampf(vacc[j][r] - 0.25f * macc[j][r]);
        Vf[(w * 16 + lgrp * 4 + r) * VST + j * 16 + lane16] = v;
        short hi, lo; split1(v, hi, lo);
        hv[r] = hi; lv[r] = lo;
      }
      const int base = (j * 16 + lane16) * BST + w * 16 + lgrp * 4;
      *(short4v*)&Bth[base] = hv;
      *(short4v*)&Btl[base] = lv;
    }
    __syncthreads();
  }

  // ------- tail: W2 = Vinv @ k3v ;  w2t[dd][m] = W2[m][dd] -------
  const float* kvp = k3v + (size_t)bh * NL * HD;
  for (int i = t; i < NL * HD; i += 512) {
    int rr = i >> 6, dd = i & 63;
    float f = kvp[i];
    short hi, lo; split1(f, hi, lo);
    Bth[dd * BST + rr] = hi;
    Btl[dd * BST + rr] = lo;
  }
  __syncthreads();

  const int wr = (w & 3);    // dd row-tile (4 x 16 = 64 rows)
  const int wc = (w >> 2);   // m half (2 x 64 cols)
  f32x4 oacc[4];
#pragma unroll
  for (int j = 0; j < 4; j++) oacc[j] = f32x4{0.f, 0.f, 0.f, 0.f};
#pragma unroll
  for (int kk = 0; kk < 4; kk++) {
    const int ao = (wr * 16 + lane16) * BST + kk * 32 + lgrp * 8;
    bf16x8 ahi = *(const bf16x8*)&Bth[ao];
    bf16x8 alo = *(const bf16x8*)&Btl[ao];
#pragma unroll
    for (int j = 0; j < 4; j++) {
      const float* bp = &Vf[((wc * 4 + j) * 16 + lane16) * VST + kk * 32 + lgrp * 8];
      f32x4 b0 = *(const f32x4*)bp;
      f32x4 b1 = *(const f32x4*)(bp + 4);
      float bvv[8] = {b0[0], b0[1], b0[2], b0[3], b1[0], b1[1], b1[2], b1[3]};
      bf16x8 bhv, blv;
      split8(bvv, bhv, blv);
      oacc[j] = mfma16(alo, bhv, oacc[j]);
      oacc[j] = mfma16(ahi, blv, oacc[j]);
      oacc[j] = mfma16(ahi, bhv, oacc[j]);
    }
  }
  unsigned short* outp = w2t + (size_t)bh * HD * NL;
#pragma unroll
  for (int j = 0; j < 4; j++)
#pragma unroll
    for (int r = 0; r < 4; r++) {
      int dd = wr * 16 + lgrp * 4 + r;
      int m  = (wc * 4 + j) * 16 + lane16;
      outp[(size_t)dd * NL + m] = (unsigned short)f2bf(clampf(oacc[j][r]));
    }
}

// ---------------------------------------------------------------------------
// Kernel 7: out = softmax_rows(Q @ Klm^T) @ W2 -> FP32 output.
// ---------------------------------------------------------------------------
__global__ __launch_bounds__(256, 2) void final_kernel(
    const unsigned short* __restrict__ Q, const unsigned short* __restrict__ Klmb,
    const unsigned short* __restrict__ w2t, float* __restrict__ outp)
{
  constexpr int KSD = 72;
  constexpr int PSD = 136;
  __shared__ __align__(16) short klm_s[NL * KSD];
  __shared__ __align__(16) short p_s[NL * PSD];

  const int bid = blockIdx.x;
  const int bh = bid >> 5, lt = bid & 31;
  const int l0 = lt * NL;
  const int t = threadIdx.x, w = t >> 6, l = t & 63;
  const int lane16 = l & 15, lgrp = l >> 4;
  const int wm = w * 32;
  const unsigned short* Qp = Q + (size_t)bh * LL * HD;
  const unsigned short* Kp = Klmb + (size_t)bh * NL * HD;
  const unsigned short* Wp = w2t + (size_t)bh * HD * NL;

  for (int i = t; i < NL * HD / 4; i += 256) {
    int flat = i * 4, rr = flat >> 6, dd = flat & 63;
    *(uint2*)&klm_s[rr * KSD + dd] = *(const uint2*)&Kp[flat];
  }
  __syncthreads();

  f32x4 sacc[2][8];
#pragma unroll
  for (int i = 0; i < 2; i++)
#pragma unroll
    for (int j = 0; j < 8; j++) sacc[i][j] = f32x4{0.f, 0.f, 0.f, 0.f};
#pragma unroll
  for (int kc = 0; kc < 2; kc++) {
    bf16x8 aq[2];
#pragma unroll
    for (int i = 0; i < 2; i++)
      aq[i] = *(const bf16x8*)&Qp[(size_t)(l0 + wm + i * 16 + lane16) * HD + kc * 32 + lgrp * 8];
#pragma unroll
    for (int j = 0; j < 8; j++) {
      bf16x8 bk = *(const bf16x8*)&klm_s[(j * 16 + lane16) * KSD + kc * 32 + lgrp * 8];
#pragma unroll
      for (int i = 0; i < 2; i++) sacc[i][j] = mfma16(aq[i], bk, sacc[i][j]);
    }
  }

#pragma unroll
  for (int i = 0; i < 2; i++) {
#pragma unroll
    for (int r = 0; r < 4; r++) {
      float mx = -1e30f;
#pragma unroll
      for (int j = 0; j < 8; j++) mx = fmaxf(mx, sacc[i][j][r]);
      mx = fmaxf(mx, __shfl_xor(mx, 1, 16));
      mx = fmaxf(mx, __shfl_xor(mx, 2, 16));
      mx = fmaxf(mx, __shfl_xor(mx, 4, 16));
      mx = fmaxf(mx, __shfl_xor(mx, 8, 16));
      float sum = 0.f;
#pragma unroll
      for (int j = 0; j < 8; j++) {
        float e = __expf(sacc[i][j][r] - mx);
        sacc[i][j][r] = e;
        sum += e;
      }
      sum += __shfl_xor(sum, 1, 16);
      sum += __shfl_xor(sum, 2, 16);
      sum += __shfl_xor(sum, 4, 16);
      sum += __shfl_xor(sum, 8, 16);
      float inv = 1.0f / fmaxf(sum, 1e-30f);
      int row = wm + i * 16 + lgrp * 4 + r;
#pragma unroll
      for (int j = 0; j < 8; j++)
        p_s[row * PSD + j * 16 + lane16] = f2bf(sacc[i][j][r] * inv);
    }
  }
  __syncthreads();

  f32x4 oacc[2][4];
#pragma unroll
  for (int i = 0; i < 2; i++)
#pragma unroll
    for (int j = 0; j < 4; j++) oacc[i][j] = f32x4{0.f, 0.f, 0.f, 0.f};
#pragma unroll
  for (int kc = 0; kc < 4; kc++) {
    bf16x8 ap[2];
#pragma unroll
    for (int i = 0; i < 2; i++)
      ap[i] = *(const bf16x8*)&p_s[(wm + i * 16 + lane16) * PSD + kc * 32 + lgrp * 8];
#pragma unroll
    for (int j = 0; j < 4; j++) {
      bf16x8 bw = *(const bf16x8*)&Wp[(size_t)(j * 16 + lane16) * NL + kc * 32 + lgrp * 8];
#pragma unroll
      for (int i = 0; i < 2; i++) oacc[i][j] = mfma16(ap[i], bw, oacc[i][j]);
    }
  }

  const int b = bh >> 4, h = bh & 15;
#pragma unroll
  for (int i = 0; i < 2; i++)
#pragma unroll
    for (int j = 0; j < 4; j++)
#pragma unroll
      for (int r = 0; r < 4; r++) {
        int row = wm + i * 16 + lgrp * 4 + r;
        int dd = j * 16 + lane16;
        outp[((size_t)b * LL + l0 + row) * DM + h * HD + dd] = oacc[i][j][r];  // FP32 store
      }
}

// ---------------------------------------------------------------------------
extern "C" void kernel_launch(void* const* d_in, const int* in_sizes, int n_in,
                              void* d_out, int out_size, void* d_ws, size_t ws_size,
                              hipStream_t stream) {
  (void)in_sizes; (void)n_in; (void)out_size; (void)ws_size;
  float* outp = (float*)d_out;  // reference output dtype = float32

  char* ws = (char*)d_ws;
  size_t off = 0;
  auto alloc = [&](size_t bytes) -> void* {
    void* p = ws + off;
    off += (bytes + 255) & ~(size_t)255;
    return p;
  };
  int* flags = (int*)alloc(64);
  unsigned* alpha_bits = (unsigned*)alloc(64);
  float* colsum_g = (float*)alloc((size_t)BH * NL * 4);
  float* Qlm = (float*)alloc((size_t)BH * NL * HD * 4);
  float* Klm = (float*)alloc((size_t)BH * NL * HD * 4);
  unsigned short* Qlmb = (unsigned short*)alloc((size_t)BH * NL * HD * 2);
  unsigned short* Klmb = (unsigned short*)alloc((size_t)BH * NL * HD * 2);
  float* k2 = (float*)alloc((size_t)BH * NL * NL * 4);
  float* k3v = (float*)alloc((size_t)BH * NL * HD * 4);
  unsigned short* w2t = (unsigned short*)alloc((size_t)BH * HD * NL * 2);
  unsigned short* Wb = (unsigned short*)alloc((size_t)3 * DM * DM * 2);
  float* bb = (float*)alloc((size_t)3 * DM * 4);
  // union region: xb (bf16 x, 33.6 MB — dead after proj) aliases the k3v
  // split-K partials op/mp/lp (34.6 MB at NSPLIT=16 — written after proj).
  const size_t OP_BYTES = (size_t)BH * NSPLIT * NL * HD * 4;           // 33.55 MB
  const size_t ML_BYTES = (size_t)BH * NSPLIT * NL * 4;                // 0.5 MB
  const size_t XB_BYTES = (size_t)4 * LL * DM * 2;                     // 33.55 MB
  const size_t UB_BYTES = OP_BYTES + 2 * ML_BYTES + 512;
  char* ub = (char*)alloc(UB_BYTES > XB_BYTES ? UB_BYTES : XB_BYTES);
  unsigned short* xb = (unsigned short*)ub;
  float* op = (float*)ub;
  float* mp = (float*)(ub + OP_BYTES);
  float* lp = mp + (size_t)BH * NSPLIT * NL;
  const size_t QKV = (size_t)BH * LL * HD;
  unsigned short* Qb = (unsigned short*)alloc(QKV * 2);
  unsigned short* Kb = (unsigned short*)alloc(QKV * 2);
  unsigned short* Vb = (unsigned short*)alloc(QKV * 2);

  hipMemsetAsync(colsum_g, 0, (size_t)BH * NL * 4, stream);
  probe_kernel<<<7, 256, 0, stream>>>(
      (const unsigned short*)d_in[0], (const unsigned short*)d_in[1],
      (const unsigned short*)d_in[2], (const unsigned short*)d_in[3],
      (const unsigned short*)d_in[4], (const unsigned short*)d_in[5],
      (const unsigned short*)d_in[6], flags);
  cvtx_kernel<<<2048, 256, 0, stream>>>(d_in[0], flags, 0, xb, 4 * LL * DM / 8);
  cvtw_kernel<<<1537, 256, 0, stream>>>(
      d_in[1], d_in[3], d_in[5], d_in[2], d_in[4], d_in[6], flags, Wb, bb);
  proj_kernel<<<128 * 24, 256, 0, stream>>>(xb, Wb, bb, Qb, Kb, Vb,
                                            Qlm, Klm, Qlmb, Klmb);
  k2_kernel<<<BH * 8, 256, 0, stream>>>(Qlm, Klm, k2, colsum_g);
  alpha_kernel<<<1, 256, 0, stream>>>(colsum_g, alpha_bits);
  k3v_kernel<<<BH * NSPLIT, 256, 0, stream>>>(Qlmb, Kb, Vb, op, mp, lp);
  k3v_combine<<<BH * NL * HD / 256, 256, 0, stream>>>(op, mp, lp, k3v);
  ns_kernel<<<BH, 512, 0, stream>>>(k2, alpha_bits, k3v, w2t);
  final_kernel<<<BH * 32, 256, 0, stream>>>(Qb, Klmb, w2t, outp);
}

// Round 11
// 456.608 us; speedup vs baseline: 1.0539x; 1.0213x over previous
//
#include <hip/hip_runtime.h>
#include <hip/hip_bf16.h>
#include <stdint.h>

#define DEV __device__ __forceinline__

typedef __attribute__((ext_vector_type(8))) short bf16x8;
typedef __attribute__((ext_vector_type(4))) short short4v;
typedef __attribute__((ext_vector_type(4))) float f32x4;

static constexpr int LL = 4096;
static constexpr int NH = 16;
static constexpr int HD = 64;
static constexpr int DM = 1024;
static constexpr int NL = 128;    // landmarks
static constexpr int BH = 64;     // B*NH
static constexpr int NSPLIT = 16; // split-K factor for k3v flash
static constexpr float QK_SCALE = 0.35355339059327379f;  // 1/sqrt(sqrt(64))

DEV short f2bf(float f) {
  union { __hip_bfloat16 h; short s; } u;
  u.h = __float2bfloat16(f);
  return u.s;
}
DEV float bf2f(unsigned short s) {
  union { unsigned u; float f; } u;
  u.u = ((unsigned)s) << 16;
  return u.f;
}
DEV float clampf(float v) {  // also scrubs NaN (AMD IEEE min/max return the non-NaN operand)
  return fminf(fmaxf(v, -1e6f), 1e6f);
}

DEV f32x4 mfma16(bf16x8 a, bf16x8 b, f32x4 c) {
  return __builtin_amdgcn_mfma_f32_16x16x32_bf16(a, b, c, 0, 0, 0);
}

DEV void gl2lds16(const void* g, void* l) {
  __builtin_amdgcn_global_load_lds(
      (const __attribute__((address_space(1))) void*)g,
      (__attribute__((address_space(3))) void*)l, 16, 0, 0);
}

// hi/lo bf16 split of one fp32 value (truncate-to-bf16 hi, rounded residual lo)
DEV void split1(float f, short& hi, short& lo) {
  unsigned u = __float_as_uint(f);
  hi = (short)(u >> 16);
  lo = f2bf(f - __uint_as_float(u & 0xffff0000u));
}

// split 8 fp32 values into hi/lo bf16x8 vectors
DEV void split8(const float* av, bf16x8& hv, bf16x8& lv) {
#pragma unroll
  for (int e = 0; e < 8; e++) {
    short hi, lo;
    split1(av[e], hi, lo);
    hv[e] = hi;
    lv[e] = lo;
  }
}

// ---------------------------------------------------------------------------
// Kernel 0 (MERGED converters + inline dtype probe): one launch replaces
// probe + cvtx + cvtw (3 launches, 2 dependency stalls).  Each block probes
// its OWN source buffer (512 even-position shorts: bf16 -> sane exponent
// ~100%, fp32 -> ~27%) then converts.
//   bid <  1536 : W conversion (512 blocks per matrix, 1 elem8/thread)
//   bid == 1536 : the 3 biases -> fp32
//   bid >  1536 : x conversion (2048 blocks, 4 elem8/thread)
// ---------------------------------------------------------------------------
__global__ __launch_bounds__(256) void cvt_kernel(
    const void* __restrict__ xv,
    const void* __restrict__ Wq, const void* __restrict__ Wk, const void* __restrict__ Wv,
    const void* __restrict__ bq, const void* __restrict__ bk, const void* __restrict__ bv,
    unsigned short* __restrict__ xb, unsigned short* __restrict__ Wb,
    float* __restrict__ bb)
{
  const int bid = blockIdx.x, t = threadIdx.x;
  __shared__ int cnt;

  auto probe_f32 = [&](const unsigned short* p) -> int {
    if (t == 0) cnt = 0;
    __syncthreads();
    int c = 0;
    for (int i = t; i < 512; i += 256) {
      unsigned e = (p[2 * i] >> 7) & 0xFF;
      if (e > 90 && e < 160) c++;
    }
    atomicAdd(&cnt, c);
    __syncthreads();
    int r = (cnt < 358);   // <70% sane => fp32
    __syncthreads();       // reads done before any later cnt reset
    return r;
  };

  auto cvt8 = [&](const void* src, unsigned short* dst, size_t i, int f32) {
    if (f32) {
      const float* s = (const float*)src + i * 8;
      f32x4 a = *(const f32x4*)s;
      f32x4 b = *(const f32x4*)(s + 4);
      bf16x8 o;
      o[0] = f2bf(a[0]); o[1] = f2bf(a[1]); o[2] = f2bf(a[2]); o[3] = f2bf(a[3]);
      o[4] = f2bf(b[0]); o[5] = f2bf(b[1]); o[6] = f2bf(b[2]); o[7] = f2bf(b[3]);
      *(bf16x8*)(dst + i * 8) = o;
    } else {
      *(bf16x8*)(dst + i * 8) =
          *(const bf16x8*)((const unsigned short*)src + i * 8);
    }
  };

  if (bid < 1536) {
    const int q = bid / 512;
    const void* src = (q == 0) ? Wq : ((q == 1) ? Wk : Wv);
    const int f32 = probe_f32((const unsigned short*)src);
    const size_t i = (size_t)(bid % 512) * 256 + t;
    cvt8(src, Wb + (size_t)q * DM * DM, i, f32);
  } else if (bid == 1536) {
    for (int q = 0; q < 3; q++) {
      const void* src = (q == 0) ? bq : ((q == 1) ? bk : bv);
      const int f32 = probe_f32((const unsigned short*)src);
      for (int i = t; i < DM; i += 256)
        bb[q * DM + i] = f32 ? ((const float*)src)[i]
                             : bf2f(((const unsigned short*)src)[i]);
      __syncthreads();
    }
  } else {
    const int xi = bid - 1537;  // 0..2047
    const int f32 = probe_f32((const unsigned short*)xv);
#pragma unroll
    for (int k = 0; k < 4; k++) {
      const size_t i = (size_t)xi * 1024 + k * 256 + t;
      cvt8(xv, xb, i, f32);
    }
  }
}

// ---------------------------------------------------------------------------
// Kernel 1 (BK=64, two-panel LDS): one output (Q|K|V) x one 128-col tile per
// block.  Landmark means written in BOTH fp32 (k2) and bf16 (k3v/final).
// ---------------------------------------------------------------------------
__global__ __launch_bounds__(256, 2) void proj_kernel(
    const unsigned short* __restrict__ xb,
    const unsigned short* __restrict__ Wb,
    const float* __restrict__ bb,
    unsigned short* __restrict__ Qo, unsigned short* __restrict__ Ko,
    unsigned short* __restrict__ Vo,
    float* __restrict__ Qlm, float* __restrict__ Klm,
    unsigned short* __restrict__ Qlmb, unsigned short* __restrict__ Klmb)
{
  __shared__ __align__(16) short As[2][128 * 32];
  __shared__ __align__(16) short Bs[2][128 * 32];

  const int t = threadIdx.x;
  const int w = t >> 6;
  const int l = t & 63;
  const int lane16 = l & 15, lgrp = l >> 4;

  const int bid = blockIdx.x;
  const int mt = bid & 127;
  const int nt = bid >> 7;
  const int which = nt >> 3;  // 0=Q 1=K 2=V
  const int m0 = mt * 128;
  const int ncol0 = (nt & 7) * 128;

  unsigned short* outp = (which == 0) ? Qo : ((which == 1) ? Ko : Vo);
  const float scl = (which == 2) ? 1.0f : QK_SCALE;

  const int srow = w * 16 + (l >> 2);
  const int skc = (l & 3) * 8;
  const unsigned short* gA = xb + (size_t)(m0 + srow) * DM + skc;
  const unsigned short* gB = Wb + (size_t)which * DM * DM + (size_t)(ncol0 + srow) * DM + skc;
  short* lA0 = As[0] + w * 512;  // wave-uniform base for gl2lds (HW adds lane*16B)
  short* lA1 = As[1] + w * 512;
  short* lB0 = Bs[0] + w * 512;
  short* lB1 = Bs[1] + w * 512;

  const int wm = (w >> 1) * 64;
  const int wn = (w & 1) * 64;

  f32x4 acc[4][4];
#pragma unroll
  for (int i = 0; i < 4; i++)
#pragma unroll
    for (int j = 0; j < 4; j++) acc[i][j] = f32x4{0.f, 0.f, 0.f, 0.f};

  for (int kk = 0; kk < DM; kk += 64) {
    gl2lds16(gA + kk, lA0);
    gl2lds16(gA + kk + 64 * DM, lA0 + 2048);
    gl2lds16(gA + kk + 32, lA1);
    gl2lds16(gA + kk + 32 + 64 * DM, lA1 + 2048);
    gl2lds16(gB + kk, lB0);
    gl2lds16(gB + kk + 64 * DM, lB0 + 2048);
    gl2lds16(gB + kk + 32, lB1);
    gl2lds16(gB + kk + 32 + 64 * DM, lB1 + 2048);
    __syncthreads();
#pragma unroll
    for (int kc = 0; kc < 2; kc++) {
      bf16x8 af[4], bfv[4];
#pragma unroll
      for (int i = 0; i < 4; i++) {
        af[i]  = *(const bf16x8*)&As[kc][(wm + i * 16 + lane16) * 32 + lgrp * 8];
        bfv[i] = *(const bf16x8*)&Bs[kc][(wn + i * 16 + lane16) * 32 + lgrp * 8];
      }
#pragma unroll
      for (int i = 0; i < 4; i++)
#pragma unroll
        for (int j = 0; j < 4; j++)
          acc[i][j] = mfma16(af[i], bfv[j], acc[i][j]);
    }
    __syncthreads();
  }

  const int b = m0 >> 12;
  const int hh = (ncol0 + wn) >> 6;
  float bv4[4];
#pragma unroll
  for (int j = 0; j < 4; j++)
    bv4[j] = bb[which * DM + ncol0 + wn + j * 16 + lane16];

  float seg[2][4];
#pragma unroll
  for (int s = 0; s < 2; s++)
#pragma unroll
    for (int j = 0; j < 4; j++) seg[s][j] = 0.f;

#pragma unroll
  for (int i = 0; i < 4; i++) {
#pragma unroll
    for (int j = 0; j < 4; j++) {
#pragma unroll
      for (int r = 0; r < 4; r++) {
        float v = (acc[i][j][r] + bv4[j]) * scl;
        int row = wm + i * 16 + lgrp * 4 + r;
        int li = (m0 + row) & 4095;
        int dd = (wn + j * 16 + lane16) & 63;
        outp[(((size_t)(b * NH + hh)) * LL + li) * HD + dd] = (unsigned short)f2bf(v);
        seg[i >> 1][j] += v;
      }
    }
  }
  if (which < 2) {
    float* lmb = (which == 0) ? Qlm : Klm;
    unsigned short* lmbb = (which == 0) ? Qlmb : Klmb;
#pragma unroll
    for (int s = 0; s < 2; s++) {
#pragma unroll
      for (int j = 0; j < 4; j++) {
        float ssum = seg[s][j];
        ssum += __shfl_xor(ssum, 16, 64);
        ssum += __shfl_xor(ssum, 32, 64);
        if (lgrp == 0) {
          int m = ((m0 + wm + s * 32) & 4095) >> 5;
          int dd = (wn + j * 16 + lane16) & 63;
          float mv = clampf(ssum * (1.0f / 32.0f));
          size_t idx = (((size_t)(b * NH + hh)) * NL + m) * HD + dd;
          lmb[idx] = mv;
          lmbb[idx] = (unsigned short)f2bf(mv);
        }
      }
    }
  }
}

// ---------------------------------------------------------------------------
// Kernel 3: kernel_2 = softmax(Qlm @ Klm^T) fp32, re-partitioned (512 blocks,
// dots cached in registers).  Partial colsums -> global via atomicAdd.
// ---------------------------------------------------------------------------
__global__ __launch_bounds__(256, 1) void k2_kernel(
    const float* __restrict__ Qlm, const float* __restrict__ Klm,
    float* __restrict__ k2, float* __restrict__ colsum_g)
{
  __shared__ float cs[NL];
  const int bid = blockIdx.x;
  const int bh = bid >> 3;
  const int rc = bid & 7;            // 16-row chunk
  const int t = threadIdx.x;
  const int r = t >> 4;              // local row 0..15
  const int c = t & 15;              // col lane 0..15
  const int row = rc * 16 + r;
  const float* Q = Qlm + ((size_t)bh * NL + row) * HD;
  const float* K = Klm + (size_t)bh * NL * HD;
  float* k2p = k2 + (size_t)bh * NL * NL;

  for (int i = t; i < NL; i += 256) cs[i] = 0.f;

  f32x4 q4[16];
#pragma unroll
  for (int d = 0; d < 16; d++) q4[d] = *(const f32x4*)&Q[d * 4];

  float dots[8];
#pragma unroll
  for (int g = 0; g < 8; g++) {
    const float* kr = K + (size_t)(c + g * 16) * HD;
    float s = 0.f;
#pragma unroll
    for (int d = 0; d < 16; d++) {
      f32x4 k4 = *(const f32x4*)&kr[d * 4];
      s += q4[d][0] * k4[0];
      s += q4[d][1] * k4[1];
      s += q4[d][2] * k4[2];
      s += q4[d][3] * k4[3];
    }
    dots[g] = s;
  }

  float mx = dots[0];
#pragma unroll
  for (int g = 1; g < 8; g++) mx = fmaxf(mx, dots[g]);
  mx = fmaxf(mx, __shfl_xor(mx, 1, 16));
  mx = fmaxf(mx, __shfl_xor(mx, 2, 16));
  mx = fmaxf(mx, __shfl_xor(mx, 4, 16));
  mx = fmaxf(mx, __shfl_xor(mx, 8, 16));

  float sum = 0.f;
#pragma unroll
  for (int g = 0; g < 8; g++) {
    float e = __expf(dots[g] - mx);
    dots[g] = e;
    sum += e;
  }
  sum += __shfl_xor(sum, 1, 16);
  sum += __shfl_xor(sum, 2, 16);
  sum += __shfl_xor(sum, 4, 16);
  sum += __shfl_xor(sum, 8, 16);
  const float inv = 1.0f / fmaxf(sum, 1e-30f);

  __syncthreads();  // cs init complete
#pragma unroll
  for (int g = 0; g < 8; g++) {
    float p = dots[g] * inv;
    k2p[(size_t)row * NL + c + g * 16] = p;
    atomicAdd(&cs[c + g * 16], p);
  }
  __syncthreads();
  for (int i = t; i < NL; i += 256) atomicAdd(&colsum_g[bh * NL + i], cs[i]);
}

// ---------------------------------------------------------------------------
// Kernel 4 (SPLIT-K, NSPLIT=16): partial flash over L-range [sp*256, +256).
// ---------------------------------------------------------------------------
__global__ __launch_bounds__(256, 1) void k3v_kernel(
    const unsigned short* __restrict__ Qlmb, const unsigned short* __restrict__ K,
    const unsigned short* __restrict__ V,
    float* __restrict__ op, float* __restrict__ mp, float* __restrict__ lp)
{
  constexpr int LT = 64;
  constexpr int ST = 72;
  __shared__ __align__(16) short q_s[NL * ST];
  __shared__ __align__(16) short k_s[LT * ST];
  __shared__ __align__(16) short vt_s[HD * ST];
  __shared__ __align__(16) short p_s[NL * ST];

  const int bid = blockIdx.x;
  const int bh = bid >> 4;           // NSPLIT = 16
  const int sp = bid & (NSPLIT - 1);
  const int t = threadIdx.x;
  const int w = t >> 6, l = t & 63;
  const int lane16 = l & 15, lgrp = l >> 4;
  const int wm = w * 32;
  const unsigned short* Kp = K + (size_t)bh * LL * HD;
  const unsigned short* Vp = V + (size_t)bh * LL * HD;

  for (int i = t; i < NL * HD / 4; i += 256) {
    int flat = i * 4, rr = flat >> 6, dd = flat & 63;
    *(uint2*)&q_s[rr * ST + dd] = *(const uint2*)&Qlmb[(size_t)bh * NL * HD + flat];
  }

  f32x4 oacc[2][4];
  float mrun[2][4], lrun[2][4];
#pragma unroll
  for (int i = 0; i < 2; i++)
#pragma unroll
    for (int j = 0; j < 4; j++) oacc[i][j] = f32x4{0.f, 0.f, 0.f, 0.f};
#pragma unroll
  for (int i = 0; i < 2; i++)
#pragma unroll
    for (int r = 0; r < 4; r++) { mrun[i][r] = -3.0e38f; lrun[i][r] = 0.f; }

  constexpr int TPS = LL / LT / NSPLIT;  // tiles per split = 4
  for (int lt = sp * TPS; lt < (sp + 1) * TPS; lt++) {
    const int l0 = lt * LT;
    for (int i = t; i < LT * HD / 4; i += 256) {
      int flat = i * 4, rr = flat >> 6, dd = flat & 63;
      *(uint2*)&k_s[rr * ST + dd] = *(const uint2*)&Kp[(size_t)(l0 + rr) * HD + dd];
      uint2 raw = *(const uint2*)&Vp[(size_t)(l0 + rr) * HD + dd];
      vt_s[(dd + 0) * ST + rr] = (short)(raw.x & 0xffff);
      vt_s[(dd + 1) * ST + rr] = (short)(raw.x >> 16);
      vt_s[(dd + 2) * ST + rr] = (short)(raw.y & 0xffff);
      vt_s[(dd + 3) * ST + rr] = (short)(raw.y >> 16);
    }
    __syncthreads();

    f32x4 sacc[2][4];
#pragma unroll
    for (int i = 0; i < 2; i++)
#pragma unroll
      for (int j = 0; j < 4; j++) sacc[i][j] = f32x4{0.f, 0.f, 0.f, 0.f};
#pragma unroll
    for (int kc = 0; kc < 2; kc++) {
      bf16x8 aq[2];
#pragma unroll
      for (int i = 0; i < 2; i++)
        aq[i] = *(const bf16x8*)&q_s[(wm + i * 16 + lane16) * ST + kc * 32 + lgrp * 8];
#pragma unroll
      for (int j = 0; j < 4; j++) {
        bf16x8 bk = *(const bf16x8*)&k_s[(j * 16 + lane16) * ST + kc * 32 + lgrp * 8];
#pragma unroll
        for (int i = 0; i < 2; i++) sacc[i][j] = mfma16(aq[i], bk, sacc[i][j]);
      }
    }

#pragma unroll
    for (int i = 0; i < 2; i++) {
#pragma unroll
      for (int r = 0; r < 4; r++) {
        float tm = fmaxf(fmaxf(sacc[i][0][r], sacc[i][1][r]),
                         fmaxf(sacc[i][2][r], sacc[i][3][r]));
        tm = fmaxf(tm, __shfl_xor(tm, 1, 16));
        tm = fmaxf(tm, __shfl_xor(tm, 2, 16));
        tm = fmaxf(tm, __shfl_xor(tm, 4, 16));
        tm = fmaxf(tm, __shfl_xor(tm, 8, 16));
        float mnew = fmaxf(mrun[i][r], tm);
        float al = __expf(mrun[i][r] - mnew);
        float rs = 0.f;
#pragma unroll
        for (int j = 0; j < 4; j++) {
          float e = __expf(sacc[i][j][r] - mnew);
          sacc[i][j][r] = e;
          rs += e;
        }
        rs += __shfl_xor(rs, 1, 16);
        rs += __shfl_xor(rs, 2, 16);
        rs += __shfl_xor(rs, 4, 16);
        rs += __shfl_xor(rs, 8, 16);
        lrun[i][r] = lrun[i][r] * al + rs;
        mrun[i][r] = mnew;
#pragma unroll
        for (int j = 0; j < 4; j++) oacc[i][j][r] *= al;
        int row = wm + i * 16 + lgrp * 4 + r;
#pragma unroll
        for (int j = 0; j < 4; j++)
          p_s[row * ST + j * 16 + lane16] = f2bf(sacc[i][j][r]);
      }
    }
    __syncthreads();

#pragma unroll
    for (int kc = 0; kc < 2; kc++) {
      bf16x8 ap[2];
#pragma unroll
      for (int i = 0; i < 2; i++)
        ap[i] = *(const bf16x8*)&p_s[(wm + i * 16 + lane16) * ST + kc * 32 + lgrp * 8];
#pragma unroll
      for (int j = 0; j < 4; j++) {
        bf16x8 bv = *(const bf16x8*)&vt_s[(j * 16 + lane16) * ST + kc * 32 + lgrp * 8];
#pragma unroll
        for (int i = 0; i < 2; i++) oacc[i][j] = mfma16(ap[i], bv, oacc[i][j]);
      }
    }
    __syncthreads();
  }

  // unnormalized partial out + per-row m,l
  float* opp = op + ((size_t)(bh * NSPLIT + sp)) * NL * HD;
#pragma unroll
  for (int i = 0; i < 2; i++)
#pragma unroll
    for (int j = 0; j < 4; j++)
#pragma unroll
      for (int r = 0; r < 4; r++) {
        int row = wm + i * 16 + lgrp * 4 + r;
        int dd = j * 16 + lane16;
        opp[(size_t)row * HD + dd] = oacc[i][j][r];
      }
  if (lane16 == 0) {
    const size_t base = (size_t)(bh * NSPLIT + sp) * NL;
#pragma unroll
    for (int i = 0; i < 2; i++)
#pragma unroll
      for (int r = 0; r < 4; r++) {
        int row = wm + i * 16 + lgrp * 4 + r;
        mp[base + row] = mrun[i][r];
        lp[base + row] = lrun[i][r];
      }
  }
}

// ---------------------------------------------------------------------------
// Kernel 4b: combine NSPLIT flash partials -> k3v fp32 (2048 blocks — the
// high-occupancy read of the 33.5 MB partials).
// ---------------------------------------------------------------------------
__global__ __launch_bounds__(256) void k3v_combine(
    const float* __restrict__ op, const float* __restrict__ mp,
    const float* __restrict__ lp, float* __restrict__ k3v)
{
  const int idx = blockIdx.x * 256 + threadIdx.x;  // over BH*NL*HD
  const int dd = idx & 63;
  const int row = (idx >> 6) & 127;
  const int bh = idx >> 13;
  (void)dd;
  float m = -3.0e38f;
  float ms[NSPLIT];
#pragma unroll
  for (int s = 0; s < NSPLIT; s++) {
    ms[s] = mp[(size_t)(bh * NSPLIT + s) * NL + row];
    m = fmaxf(m, ms[s]);
  }
  float o = 0.f, ltot = 0.f;
#pragma unroll
  for (int s = 0; s < NSPLIT; s++) {
    float sc = __expf(ms[s] - m);
    ltot += lp[(size_t)(bh * NSPLIT + s) * NL + row] * sc;
    o += op[((size_t)(bh * NSPLIT + s) * NL + row) * HD + dd] * sc;
  }
  k3v[idx] = clampf(o / fmaxf(ltot, 1e-30f));
}

// ---------------------------------------------------------------------------
// Kernel 5: Newton-Schulz pseudo-inverse, 6 iterations, hi/lo-split bf16 MFMA,
// fully LDS-resident (8-barrier/iter form — the proven register-friendly
// structure).  Prologue: inline alpha = max(colsum_g) (replaces the 1-block
// alpha_kernel launch).  Tail: W2 = Vinv @ k3v.
// ---------------------------------------------------------------------------
__global__ __launch_bounds__(512, 1) void ns_kernel(
    const float* __restrict__ k2, const float* __restrict__ colsum_g,
    const float* __restrict__ k3v, unsigned short* __restrict__ w2t)
{
  constexpr int VST = 132;   // fp32 row stride: 132 mod 32 = 4 -> 2-way (free) banks
  constexpr int BST = 136;   // bf16 row stride: 68 dwords -> uniform b128 starts
  __shared__ __align__(16) float Vf[NL * VST];    // 67.6 KB
  __shared__ __align__(16) short Bth[NL * BST];   // 34.8 KB
  __shared__ __align__(16) short Btl[NL * BST];   // 34.8 KB  (total ~137 KB < 160 KB)
  __shared__ float wmx[8];
  __shared__ float amax_s;

  const int bh = blockIdx.x, t = threadIdx.x;
  const int w = t >> 6, l = t & 63;
  const int lane16 = l & 15, lgrp = l >> 4;
  const float* K2 = k2 + (size_t)bh * NL * NL;

  // --- inline alpha: max over all colsums (32 KB, L2-served) ---
  float am = 0.f;  // colsums are sums of softmax probs >= 0
  for (int i = t; i < BH * NL; i += 512) am = fmaxf(am, colsum_g[i]);
#pragma unroll
  for (int o = 1; o < 64; o <<= 1) am = fmaxf(am, __shfl_xor(am, o, 64));
  if (l == 0) wmx[w] = am;
  __syncthreads();
  if (t == 0) {
    float m = wmx[0];
#pragma unroll
    for (int i = 1; i < 8; i++) m = fmaxf(m, wmx[i]);
    amax_s = m;
  }
  __syncthreads();
  const float inva = 1.0f / fmaxf(amax_s, 1e-30f);

  // --- K2 A-fragments (hi/lo) into registers, once (64 VGPRs) ---
  bf16x8 k2hi[4], k2lo[4];
#pragma unroll
  for (int kk = 0; kk < 4; kk++) {
    const float* ap = K2 + (size_t)(w * 16 + lane16) * NL + kk * 32 + lgrp * 8;
    f32x4 a0 = *(const f32x4*)ap;
    f32x4 a1 = *(const f32x4*)(ap + 4);
    float av[8] = {a0[0], a0[1], a0[2], a0[3], a1[0], a1[1], a1[2], a1[3]};
    split8(av, k2hi[kk], k2lo[kk]);
  }

  // --- init: V = clamp(K2^T * inva) -> Vf row-major; Bt = V^T = clamp(K2*inva)
  for (int i = t; i < NL * NL; i += 512) {
    int rr = i >> 7, cc = i & 127;
    float v = clampf(K2[(size_t)cc * NL + rr] * inva);
    Vf[rr * VST + cc] = v;
    short hi, lo; split1(v, hi, lo);
    Bth[cc * BST + rr] = hi;
    Btl[cc * BST + rr] = lo;
  }
  __syncthreads();

  f32x4 macc[8], vacc[8];

  // macc = A @ B  with A-fragments in registers, B = Bt (transposed hi/lo)
  auto mmA = [&](const bf16x8* ahi, const bf16x8* alo) {
#pragma unroll
    for (int j = 0; j < 8; j++) macc[j] = f32x4{0.f, 0.f, 0.f, 0.f};
#pragma unroll
    for (int kk = 0; kk < 4; kk++) {
#pragma unroll
      for (int j = 0; j < 8; j++) {
        const int bo = (j * 16 + lane16) * BST + kk * 32 + lgrp * 8;
        bf16x8 bh_ = *(const bf16x8*)&Bth[bo];
        bf16x8 bl_ = *(const bf16x8*)&Btl[bo];
        macc[j] = mfma16(alo[kk], bh_, macc[j]);
        macc[j] = mfma16(ahi[kk], bl_, macc[j]);
        macc[j] = mfma16(ahi[kk], bh_, macc[j]);
      }
    }
  };

  // macc = Vf @ B (A rows = this wave's 16 rows of Vf, split on the fly)
  auto mmV = [&]() {
    bf16x8 ahi[4], alo[4];
#pragma unroll
    for (int kk = 0; kk < 4; kk++) {
      const float* ap = &Vf[(w * 16 + lane16) * VST + kk * 32 + lgrp * 8];
      f32x4 a0 = *(const f32x4*)ap;
      f32x4 a1 = *(const f32x4*)(ap + 4);
      float av[8] = {a0[0], a0[1], a0[2], a0[3], a1[0], a1[1], a1[2], a1[3]};
      split8(av, ahi[kk], alo[kk]);
    }
    mmA(ahi, alo);
  };

  // Bt <- clamp(macc)^T  (packed b64 writes: 4 consecutive rows per lane)
  auto writeBt = [&]() {
#pragma unroll
    for (int j = 0; j < 8; j++) {
      short4v hv, lv;
#pragma unroll
      for (int r = 0; r < 4; r++) {
        float c = clampf(macc[j][r]);
        short hi, lo; split1(c, hi, lo);
        hv[r] = hi; lv[r] = lo;
      }
      const int base = (j * 16 + lane16) * BST + w * 16 + lgrp * 4;
      *(short4v*)&Bth[base] = hv;
      *(short4v*)&Btl[base] = lv;
    }
  };

  for (int it = 0; it < 6; it++) {
    // KV = K2 @ V   (B = Bt holding V^T)
    mmA(k2hi, k2lo);
    __syncthreads();              // all waves done reading Bt(V^T)
    writeBt();                    // Bt <- KV^T (clamped), B for mm2..mm4
    __syncthreads();

    // M1 = V @ KV ; vacc = 3.25*V - 3.75*M1
    mmV();
#pragma unroll
    for (int j = 0; j < 8; j++)
#pragma unroll
      for (int r = 0; r < 4; r++)
        vacc[j][r] = 3.25f * Vf[(w * 16 + lgrp * 4 + r) * VST + j * 16 + lane16]
                   - 3.75f * macc[j][r];
    __syncthreads();
#pragma unroll
    for (int j = 0; j < 8; j++)
#pragma unroll
      for (int r = 0; r < 4; r++)
        Vf[(w * 16 + lgrp * 4 + r) * VST + j * 16 + lane16] = clampf(macc[j][r]);
    __syncthreads();

    // M2 = M1 @ KV ; vacc += 1.75*M2
    mmV();
#pragma unroll
    for (int j = 0; j < 8; j++)
#pragma unroll
      for (int r = 0; r < 4; r++) vacc[j][r] += 1.75f * macc[j][r];
    __syncthreads();
#pragma unroll
    for (int j = 0; j < 8; j++)
#pragma unroll
      for (int r = 0; r < 4; r++)
        Vf[(w * 16 + lgrp * 4 + r) * VST + j * 16 + lane16] = clampf(macc[j][r]);
    __syncthreads();

    // M3 = M2 @ KV ; V_new = clamp(vacc - 0.25*M3) -> Vf + Bt (for next iter)
    mmV();
    __syncthreads();              // all waves done reading Bt(KV^T) + Vf(M2)
#pragma unroll
    for (int j = 0; j < 8; j++) {
      short4v hv, lv;
#pragma unroll
      for (int r = 0; r < 4; r++) {
        float v = clampf(vacc[j][r] - 0.25f * macc[j][r]);
        Vf[(w * 16 + lgrp * 4 + r) * VST + j * 16 + lane16] = v;
        short hi, lo; split1(v, hi, lo);
        hv[r] = hi; lv[r] = lo;
      }
      const int base = (j * 16 + lane16) * BST + w * 16 + lgrp * 4;
      *(short4v*)&Bth[base] = hv;
      *(short4v*)&Btl[base] = lv;
    }
    __syncthreads();
  }

  // ------- tail: W2 = Vinv @ k3v ;  w2t[dd][m] = W2[m][dd] -------
  const float* kvp = k3v + (size_t)bh * NL * HD;
  for (int i = t; i < NL * HD; i += 512) {
    int rr = i >> 6, dd = i & 63;
    float f = kvp[i];
    short hi, lo; split1(f, hi, lo);
    Bth[dd * BST + rr] = hi;
    Btl[dd * BST + rr] = lo;
  }
  __syncthreads();

  const int wr = (w & 3);    // dd row-tile (4 x 16 = 64 rows)
  const int wc = (w >> 2);   // m half (2 x 64 cols)
  f32x4 oacc[4];
#pragma unroll
  for (int j = 0; j < 4; j++) oacc[j] = f32x4{0.f, 0.f, 0.f, 0.f};
#pragma unroll
  for (int kk = 0; kk < 4; kk++) {
    const int ao = (wr * 16 + lane16) * BST + kk * 32 + lgrp * 8;
    bf16x8 ahi = *(const bf16x8*)&Bth[ao];
    bf16x8 alo = *(const bf16x8*)&Btl[ao];
#pragma unroll
    for (int j = 0; j < 4; j++) {
      const float* bp = &Vf[((wc * 4 + j) * 16 + lane16) * VST + kk * 32 + lgrp * 8];
      f32x4 b0 = *(const f32x4*)bp;
      f32x4 b1 = *(const f32x4*)(bp + 4);
      float bvv[8] = {b0[0], b0[1], b0[2], b0[3], b1[0], b1[1], b1[2], b1[3]};
      bf16x8 bhv, blv;
      split8(bvv, bhv, blv);
      oacc[j] = mfma16(alo, bhv, oacc[j]);
      oacc[j] = mfma16(ahi, blv, oacc[j]);
      oacc[j] = mfma16(ahi, bhv, oacc[j]);
    }
  }
  unsigned short* outp = w2t + (size_t)bh * HD * NL;
#pragma unroll
  for (int j = 0; j < 4; j++)
#pragma unroll
    for (int r = 0; r < 4; r++) {
      int dd = wr * 16 + lgrp * 4 + r;
      int m  = (wc * 4 + j) * 16 + lane16;
      outp[(size_t)dd * NL + m] = (unsigned short)f2bf(clampf(oacc[j][r]));
    }
}

// ---------------------------------------------------------------------------
// Kernel 7: out = softmax_rows(Q @ Klm^T) @ W2 -> FP32 output.
// ---------------------------------------------------------------------------
__global__ __launch_bounds__(256, 2) void final_kernel(
    const unsigned short* __restrict__ Q, const unsigned short* __restrict__ Klmb,
    const unsigned short* __restrict__ w2t, float* __restrict__ outp)
{
  constexpr int KSD = 72;
  constexpr int PSD = 136;
  __shared__ __align__(16) short klm_s[NL * KSD];
  __shared__ __align__(16) short p_s[NL * PSD];

  const int bid = blockIdx.x;
  const int bh = bid >> 5, lt = bid & 31;
  const int l0 = lt * NL;
  const int t = threadIdx.x, w = t >> 6, l = t & 63;
  const int lane16 = l & 15, lgrp = l >> 4;
  const int wm = w * 32;
  const unsigned short* Qp = Q + (size_t)bh * LL * HD;
  const unsigned short* Kp = Klmb + (size_t)bh * NL * HD;
  const unsigned short* Wp = w2t + (size_t)bh * HD * NL;

  for (int i = t; i < NL * HD / 4; i += 256) {
    int flat = i * 4, rr = flat >> 6, dd = flat & 63;
    *(uint2*)&klm_s[rr * KSD + dd] = *(const uint2*)&Kp[flat];
  }
  __syncthreads();

  f32x4 sacc[2][8];
#pragma unroll
  for (int i = 0; i < 2; i++)
#pragma unroll
    for (int j = 0; j < 8; j++) sacc[i][j] = f32x4{0.f, 0.f, 0.f, 0.f};
#pragma unroll
  for (int kc = 0; kc < 2; kc++) {
    bf16x8 aq[2];
#pragma unroll
    for (int i = 0; i < 2; i++)
      aq[i] = *(const bf16x8*)&Qp[(size_t)(l0 + wm + i * 16 + lane16) * HD + kc * 32 + lgrp * 8];
#pragma unroll
    for (int j = 0; j < 8; j++) {
      bf16x8 bk = *(const bf16x8*)&klm_s[(j * 16 + lane16) * KSD + kc * 32 + lgrp * 8];
#pragma unroll
      for (int i = 0; i < 2; i++) sacc[i][j] = mfma16(aq[i], bk, sacc[i][j]);
    }
  }

#pragma unroll
  for (int i = 0; i < 2; i++) {
#pragma unroll
    for (int r = 0; r < 4; r++) {
      float mx = -1e30f;
#pragma unroll
      for (int j = 0; j < 8; j++) mx = fmaxf(mx, sacc[i][j][r]);
      mx = fmaxf(mx, __shfl_xor(mx, 1, 16));
      mx = fmaxf(mx, __shfl_xor(mx, 2, 16));
      mx = fmaxf(mx, __shfl_xor(mx, 4, 16));
      mx = fmaxf(mx, __shfl_xor(mx, 8, 16));
      float sum = 0.f;
#pragma unroll
      for (int j = 0; j < 8; j++) {
        float e = __expf(sacc[i][j][r] - mx);
        sacc[i][j][r] = e;
        sum += e;
      }
      sum += __shfl_xor(sum, 1, 16);
      sum += __shfl_xor(sum, 2, 16);
      sum += __shfl_xor(sum, 4, 16);
      sum += __shfl_xor(sum, 8, 16);
      float inv = 1.0f / fmaxf(sum, 1e-30f);
      int row = wm + i * 16 + lgrp * 4 + r;
#pragma unroll
      for (int j = 0; j < 8; j++)
        p_s[row * PSD + j * 16 + lane16] = f2bf(sacc[i][j][r] * inv);
    }
  }
  __syncthreads();

  f32x4 oacc[2][4];
#pragma unroll
  for (int i = 0; i < 2; i++)
#pragma unroll
    for (int j = 0; j < 4; j++) oacc[i][j] = f32x4{0.f, 0.f, 0.f, 0.f};
#pragma unroll
  for (int kc = 0; kc < 4; kc++) {
    bf16x8 ap[2];
#pragma unroll
    for (int i = 0; i < 2; i++)
      ap[i] = *(const bf16x8*)&p_s[(wm + i * 16 + lane16) * PSD + kc * 32 + lgrp * 8];
#pragma unroll
    for (int j = 0; j < 4; j++) {
      bf16x8 bw = *(const bf16x8*)&Wp[(size_t)(j * 16 + lane16) * NL + kc * 32 + lgrp * 8];
#pragma unroll
      for (int i = 0; i < 2; i++) oacc[i][j] = mfma16(ap[i], bw, oacc[i][j]);
    }
  }

  const int b = bh >> 4, h = bh & 15;
#pragma unroll
  for (int i = 0; i < 2; i++)
#pragma unroll
    for (int j = 0; j < 4; j++)
#pragma unroll
      for (int r = 0; r < 4; r++) {
        int row = wm + i * 16 + lgrp * 4 + r;
        int dd = j * 16 + lane16;
        outp[((size_t)b * LL + l0 + row) * DM + h * HD + dd] = oacc[i][j][r];  // FP32 store
      }
}

// ---------------------------------------------------------------------------
extern "C" void kernel_launch(void* const* d_in, const int* in_sizes, int n_in,
                              void* d_out, int out_size, void* d_ws, size_t ws_size,
                              hipStream_t stream) {
  (void)in_sizes; (void)n_in; (void)out_size; (void)ws_size;
  float* outp = (float*)d_out;  // reference output dtype = float32

  char* ws = (char*)d_ws;
  size_t off = 0;
  auto alloc = [&](size_t bytes) -> void* {
    void* p = ws + off;
    off += (bytes + 255) & ~(size_t)255;
    return p;
  };
  float* colsum_g = (float*)alloc((size_t)BH * NL * 4);
  float* Qlm = (float*)alloc((size_t)BH * NL * HD * 4);
  float* Klm = (float*)alloc((size_t)BH * NL * HD * 4);
  unsigned short* Qlmb = (unsigned short*)alloc((size_t)BH * NL * HD * 2);
  unsigned short* Klmb = (unsigned short*)alloc((size_t)BH * NL * HD * 2);
  float* k2 = (float*)alloc((size_t)BH * NL * NL * 4);
  float* k3v = (float*)alloc((size_t)BH * NL * HD * 4);
  unsigned short* w2t = (unsigned short*)alloc((size_t)BH * HD * NL * 2);
  unsigned short* Wb = (unsigned short*)alloc((size_t)3 * DM * DM * 2);
  float* bb = (float*)alloc((size_t)3 * DM * 4);
  // union region: xb (bf16 x, 33.6 MB — dead after proj) aliases the k3v
  // split-K partials op/mp/lp (34.6 MB at NSPLIT=16 — written after proj).
  const size_t OP_BYTES = (size_t)BH * NSPLIT * NL * HD * 4;           // 33.55 MB
  const size_t ML_BYTES = (size_t)BH * NSPLIT * NL * 4;                // 0.5 MB
  const size_t XB_BYTES = (size_t)4 * LL * DM * 2;                     // 33.55 MB
  const size_t UB_BYTES = OP_BYTES + 2 * ML_BYTES + 512;
  char* ub = (char*)alloc(UB_BYTES > XB_BYTES ? UB_BYTES : XB_BYTES);
  unsigned short* xb = (unsigned short*)ub;
  float* op = (float*)ub;
  float* mp = (float*)(ub + OP_BYTES);
  float* lp = mp + (size_t)BH * NSPLIT * NL;
  const size_t QKV = (size_t)BH * LL * HD;
  unsigned short* Qb = (unsigned short*)alloc(QKV * 2);
  unsigned short* Kb = (unsigned short*)alloc(QKV * 2);
  unsigned short* Vb = (unsigned short*)alloc(QKV * 2);

  hipMemsetAsync(colsum_g, 0, (size_t)BH * NL * 4, stream);
  cvt_kernel<<<3585, 256, 0, stream>>>(
      d_in[0], d_in[1], d_in[3], d_in[5], d_in[2], d_in[4], d_in[6],
      xb, Wb, bb);
  proj_kernel<<<128 * 24, 256, 0, stream>>>(xb, Wb, bb, Qb, Kb, Vb,
                                            Qlm, Klm, Qlmb, Klmb);
  k2_kernel<<<BH * 8, 256, 0, stream>>>(Qlm, Klm, k2, colsum_g);
  k3v_kernel<<<BH * NSPLIT, 256, 0, stream>>>(Qlmb, Kb, Vb, op, mp, lp);
  k3v_combine<<<BH * NL * HD / 256, 256, 0, stream>>>(op, mp, lp, k3v);
  ns_kernel<<<BH, 512, 0, stream>>>(k2, colsum_g, k3v, w2t);
  final_kernel<<<BH * 32, 256, 0, stream>>>(Qb, Klmb, w2t, outp);
}

// Round 12
// 447.814 us; speedup vs baseline: 1.0746x; 1.0196x over previous
//
#include <hip/hip_runtime.h>
#include <hip/hip_bf16.h>
#include <stdint.h>

#define DEV __device__ __forceinline__

typedef __attribute__((ext_vector_type(8))) short bf16x8;
typedef __attribute__((ext_vector_type(4))) short short4v;
typedef __attribute__((ext_vector_type(4))) float f32x4;

static constexpr int LL = 4096;
static constexpr int NH = 16;
static constexpr int HD = 64;
static constexpr int DM = 1024;
static constexpr int NL = 128;    // landmarks
static constexpr int BH = 64;     // B*NH
static constexpr int NSPLIT = 16; // split-K factor for k3v flash
static constexpr float QK_SCALE = 0.35355339059327379f;  // 1/sqrt(sqrt(64))

DEV short f2bf(float f) {
  union { __hip_bfloat16 h; short s; } u;
  u.h = __float2bfloat16(f);
  return u.s;
}
DEV float bf2f(unsigned short s) {
  union { unsigned u; float f; } u;
  u.u = ((unsigned)s) << 16;
  return u.f;
}
DEV float clampf(float v) {  // also scrubs NaN (AMD IEEE min/max return the non-NaN operand)
  return fminf(fmaxf(v, -1e6f), 1e6f);
}

DEV f32x4 mfma16(bf16x8 a, bf16x8 b, f32x4 c) {
  return __builtin_amdgcn_mfma_f32_16x16x32_bf16(a, b, c, 0, 0, 0);
}

DEV void gl2lds16(const void* g, void* l) {
  __builtin_amdgcn_global_load_lds(
      (const __attribute__((address_space(1))) void*)g,
      (__attribute__((address_space(3))) void*)l, 16, 0, 0);
}

// hi/lo bf16 split of one fp32 value (truncate-to-bf16 hi, rounded residual lo)
DEV void split1(float f, short& hi, short& lo) {
  unsigned u = __float_as_uint(f);
  hi = (short)(u >> 16);
  lo = f2bf(f - __uint_as_float(u & 0xffff0000u));
}

// split 8 fp32 values into hi/lo bf16x8 vectors
DEV void split8(const float* av, bf16x8& hv, bf16x8& lv) {
#pragma unroll
  for (int e = 0; e < 8; e++) {
    short hi, lo;
    split1(av[e], hi, lo);
    hv[e] = hi;
    lv[e] = lo;
  }
}

// ---------------------------------------------------------------------------
// Kernel 0 (MERGED converters + inline dtype probe).
//   bid <  1536 : W conversion (512 blocks per matrix, 1 elem8/thread)
//   bid == 1536 : the 3 biases -> fp32
//   bid >  1536 : x conversion (2048 blocks, 4 elem8/thread)
// ---------------------------------------------------------------------------
__global__ __launch_bounds__(256) void cvt_kernel(
    const void* __restrict__ xv,
    const void* __restrict__ Wq, const void* __restrict__ Wk, const void* __restrict__ Wv,
    const void* __restrict__ bq, const void* __restrict__ bk, const void* __restrict__ bv,
    unsigned short* __restrict__ xb, unsigned short* __restrict__ Wb,
    float* __restrict__ bb)
{
  const int bid = blockIdx.x, t = threadIdx.x;
  __shared__ int cnt;

  auto probe_f32 = [&](const unsigned short* p) -> int {
    if (t == 0) cnt = 0;
    __syncthreads();
    int c = 0;
    for (int i = t; i < 512; i += 256) {
      unsigned e = (p[2 * i] >> 7) & 0xFF;
      if (e > 90 && e < 160) c++;
    }
    atomicAdd(&cnt, c);
    __syncthreads();
    int r = (cnt < 358);   // <70% sane => fp32
    __syncthreads();       // reads done before any later cnt reset
    return r;
  };

  auto cvt8 = [&](const void* src, unsigned short* dst, size_t i, int f32) {
    if (f32) {
      const float* s = (const float*)src + i * 8;
      f32x4 a = *(const f32x4*)s;
      f32x4 b = *(const f32x4*)(s + 4);
      bf16x8 o;
      o[0] = f2bf(a[0]); o[1] = f2bf(a[1]); o[2] = f2bf(a[2]); o[3] = f2bf(a[3]);
      o[4] = f2bf(b[0]); o[5] = f2bf(b[1]); o[6] = f2bf(b[2]); o[7] = f2bf(b[3]);
      *(bf16x8*)(dst + i * 8) = o;
    } else {
      *(bf16x8*)(dst + i * 8) =
          *(const bf16x8*)((const unsigned short*)src + i * 8);
    }
  };

  if (bid < 1536) {
    const int q = bid / 512;
    const void* src = (q == 0) ? Wq : ((q == 1) ? Wk : Wv);
    const int f32 = probe_f32((const unsigned short*)src);
    const size_t i = (size_t)(bid % 512) * 256 + t;
    cvt8(src, Wb + (size_t)q * DM * DM, i, f32);
  } else if (bid == 1536) {
    for (int q = 0; q < 3; q++) {
      const void* src = (q == 0) ? bq : ((q == 1) ? bk : bv);
      const int f32 = probe_f32((const unsigned short*)src);
      for (int i = t; i < DM; i += 256)
        bb[q * DM + i] = f32 ? ((const float*)src)[i]
                             : bf2f(((const unsigned short*)src)[i]);
      __syncthreads();
    }
  } else {
    const int xi = bid - 1537;  // 0..2047
    const int f32 = probe_f32((const unsigned short*)xv);
#pragma unroll
    for (int k = 0; k < 4; k++) {
      const size_t i = (size_t)xi * 1024 + k * 256 + t;
      cvt8(xv, xb, i, f32);
    }
  }
}

// ---------------------------------------------------------------------------
// Kernel 1 (BK=64, two-panel LDS): one output (Q|K|V) x one 128-col tile per
// block.  Landmark means written in BOTH fp32 (k2) and bf16 (k3v/final).
// ---------------------------------------------------------------------------
__global__ __launch_bounds__(256, 2) void proj_kernel(
    const unsigned short* __restrict__ xb,
    const unsigned short* __restrict__ Wb,
    const float* __restrict__ bb,
    unsigned short* __restrict__ Qo, unsigned short* __restrict__ Ko,
    unsigned short* __restrict__ Vo,
    float* __restrict__ Qlm, float* __restrict__ Klm,
    unsigned short* __restrict__ Qlmb, unsigned short* __restrict__ Klmb)
{
  __shared__ __align__(16) short As[2][128 * 32];
  __shared__ __align__(16) short Bs[2][128 * 32];

  const int t = threadIdx.x;
  const int w = t >> 6;
  const int l = t & 63;
  const int lane16 = l & 15, lgrp = l >> 4;

  const int bid = blockIdx.x;
  const int mt = bid & 127;
  const int nt = bid >> 7;
  const int which = nt >> 3;  // 0=Q 1=K 2=V
  const int m0 = mt * 128;
  const int ncol0 = (nt & 7) * 128;

  unsigned short* outp = (which == 0) ? Qo : ((which == 1) ? Ko : Vo);
  const float scl = (which == 2) ? 1.0f : QK_SCALE;

  const int srow = w * 16 + (l >> 2);
  const int skc = (l & 3) * 8;
  const unsigned short* gA = xb + (size_t)(m0 + srow) * DM + skc;
  const unsigned short* gB = Wb + (size_t)which * DM * DM + (size_t)(ncol0 + srow) * DM + skc;
  short* lA0 = As[0] + w * 512;  // wave-uniform base for gl2lds (HW adds lane*16B)
  short* lA1 = As[1] + w * 512;
  short* lB0 = Bs[0] + w * 512;
  short* lB1 = Bs[1] + w * 512;

  const int wm = (w >> 1) * 64;
  const int wn = (w & 1) * 64;

  f32x4 acc[4][4];
#pragma unroll
  for (int i = 0; i < 4; i++)
#pragma unroll
    for (int j = 0; j < 4; j++) acc[i][j] = f32x4{0.f, 0.f, 0.f, 0.f};

  for (int kk = 0; kk < DM; kk += 64) {
    gl2lds16(gA + kk, lA0);
    gl2lds16(gA + kk + 64 * DM, lA0 + 2048);
    gl2lds16(gA + kk + 32, lA1);
    gl2lds16(gA + kk + 32 + 64 * DM, lA1 + 2048);
    gl2lds16(gB + kk, lB0);
    gl2lds16(gB + kk + 64 * DM, lB0 + 2048);
    gl2lds16(gB + kk + 32, lB1);
    gl2lds16(gB + kk + 32 + 64 * DM, lB1 + 2048);
    __syncthreads();
#pragma unroll
    for (int kc = 0; kc < 2; kc++) {
      bf16x8 af[4], bfv[4];
#pragma unroll
      for (int i = 0; i < 4; i++) {
        af[i]  = *(const bf16x8*)&As[kc][(wm + i * 16 + lane16) * 32 + lgrp * 8];
        bfv[i] = *(const bf16x8*)&Bs[kc][(wn + i * 16 + lane16) * 32 + lgrp * 8];
      }
#pragma unroll
      for (int i = 0; i < 4; i++)
#pragma unroll
        for (int j = 0; j < 4; j++)
          acc[i][j] = mfma16(af[i], bfv[j], acc[i][j]);
    }
    __syncthreads();
  }

  const int b = m0 >> 12;
  const int hh = (ncol0 + wn) >> 6;
  float bv4[4];
#pragma unroll
  for (int j = 0; j < 4; j++)
    bv4[j] = bb[which * DM + ncol0 + wn + j * 16 + lane16];

  float seg[2][4];
#pragma unroll
  for (int s = 0; s < 2; s++)
#pragma unroll
    for (int j = 0; j < 4; j++) seg[s][j] = 0.f;

#pragma unroll
  for (int i = 0; i < 4; i++) {
#pragma unroll
    for (int j = 0; j < 4; j++) {
#pragma unroll
      for (int r = 0; r < 4; r++) {
        float v = (acc[i][j][r] + bv4[j]) * scl;
        int row = wm + i * 16 + lgrp * 4 + r;
        int li = (m0 + row) & 4095;
        int dd = (wn + j * 16 + lane16) & 63;
        outp[(((size_t)(b * NH + hh)) * LL + li) * HD + dd] = (unsigned short)f2bf(v);
        seg[i >> 1][j] += v;
      }
    }
  }
  if (which < 2) {
    float* lmb = (which == 0) ? Qlm : Klm;
    unsigned short* lmbb = (which == 0) ? Qlmb : Klmb;
#pragma unroll
    for (int s = 0; s < 2; s++) {
#pragma unroll
      for (int j = 0; j < 4; j++) {
        float ssum = seg[s][j];
        ssum += __shfl_xor(ssum, 16, 64);
        ssum += __shfl_xor(ssum, 32, 64);
        if (lgrp == 0) {
          int m = ((m0 + wm + s * 32) & 4095) >> 5;
          int dd = (wn + j * 16 + lane16) & 63;
          float mv = clampf(ssum * (1.0f / 32.0f));
          size_t idx = (((size_t)(b * NH + hh)) * NL + m) * HD + dd;
          lmb[idx] = mv;
          lmbb[idx] = (unsigned short)f2bf(mv);
        }
      }
    }
  }
}

// ---------------------------------------------------------------------------
// Kernel 2 (MERGED mid-pipeline): k3v split-K flash (bid < BH*NSPLIT) and
// k2 landmark softmax (bid >= BH*NSPLIT) in ONE dispatch.  The two are
// independent (both consume only proj outputs) and use complementary pipes
// (MFMA vs VALU) -> co-scheduling instead of serialization, one less launch.
// k2's 512-B colsum scratch aliases q_s.
// ---------------------------------------------------------------------------
__global__ __launch_bounds__(256, 1) void mid_kernel(
    const unsigned short* __restrict__ Qlmb, const unsigned short* __restrict__ K,
    const unsigned short* __restrict__ V,
    float* __restrict__ op, float* __restrict__ mp, float* __restrict__ lp,
    const float* __restrict__ Qlm, const float* __restrict__ Klm,
    float* __restrict__ k2, float* __restrict__ colsum_g)
{
  constexpr int LT = 64;
  constexpr int ST = 72;
  __shared__ __align__(16) short q_s[NL * ST];
  __shared__ __align__(16) short k_s[LT * ST];
  __shared__ __align__(16) short vt_s[HD * ST];
  __shared__ __align__(16) short p_s[NL * ST];

  const int t = threadIdx.x;

  if (blockIdx.x < BH * NSPLIT) {
    // ---------------- k3v flash path ----------------
    const int bid = blockIdx.x;
    const int bh = bid >> 4;           // NSPLIT = 16
    const int sp = bid & (NSPLIT - 1);
    const int w = t >> 6, l = t & 63;
    const int lane16 = l & 15, lgrp = l >> 4;
    const int wm = w * 32;
    const unsigned short* Kp = K + (size_t)bh * LL * HD;
    const unsigned short* Vp = V + (size_t)bh * LL * HD;

    for (int i = t; i < NL * HD / 4; i += 256) {
      int flat = i * 4, rr = flat >> 6, dd = flat & 63;
      *(uint2*)&q_s[rr * ST + dd] = *(const uint2*)&Qlmb[(size_t)bh * NL * HD + flat];
    }

    f32x4 oacc[2][4];
    float mrun[2][4], lrun[2][4];
#pragma unroll
    for (int i = 0; i < 2; i++)
#pragma unroll
      for (int j = 0; j < 4; j++) oacc[i][j] = f32x4{0.f, 0.f, 0.f, 0.f};
#pragma unroll
    for (int i = 0; i < 2; i++)
#pragma unroll
      for (int r = 0; r < 4; r++) { mrun[i][r] = -3.0e38f; lrun[i][r] = 0.f; }

    constexpr int TPS = LL / LT / NSPLIT;  // tiles per split = 4
    for (int lt = sp * TPS; lt < (sp + 1) * TPS; lt++) {
      const int l0 = lt * LT;
      for (int i = t; i < LT * HD / 4; i += 256) {
        int flat = i * 4, rr = flat >> 6, dd = flat & 63;
        *(uint2*)&k_s[rr * ST + dd] = *(const uint2*)&Kp[(size_t)(l0 + rr) * HD + dd];
        uint2 raw = *(const uint2*)&Vp[(size_t)(l0 + rr) * HD + dd];
        vt_s[(dd + 0) * ST + rr] = (short)(raw.x & 0xffff);
        vt_s[(dd + 1) * ST + rr] = (short)(raw.x >> 16);
        vt_s[(dd + 2) * ST + rr] = (short)(raw.y & 0xffff);
        vt_s[(dd + 3) * ST + rr] = (short)(raw.y >> 16);
      }
      __syncthreads();

      f32x4 sacc[2][4];
#pragma unroll
      for (int i = 0; i < 2; i++)
#pragma unroll
        for (int j = 0; j < 4; j++) sacc[i][j] = f32x4{0.f, 0.f, 0.f, 0.f};
#pragma unroll
      for (int kc = 0; kc < 2; kc++) {
        bf16x8 aq[2];
#pragma unroll
        for (int i = 0; i < 2; i++)
          aq[i] = *(const bf16x8*)&q_s[(wm + i * 16 + lane16) * ST + kc * 32 + lgrp * 8];
#pragma unroll
        for (int j = 0; j < 4; j++) {
          bf16x8 bk = *(const bf16x8*)&k_s[(j * 16 + lane16) * ST + kc * 32 + lgrp * 8];
#pragma unroll
          for (int i = 0; i < 2; i++) sacc[i][j] = mfma16(aq[i], bk, sacc[i][j]);
        }
      }

#pragma unroll
      for (int i = 0; i < 2; i++) {
#pragma unroll
        for (int r = 0; r < 4; r++) {
          float tm = fmaxf(fmaxf(sacc[i][0][r], sacc[i][1][r]),
                           fmaxf(sacc[i][2][r], sacc[i][3][r]));
          tm = fmaxf(tm, __shfl_xor(tm, 1, 16));
          tm = fmaxf(tm, __shfl_xor(tm, 2, 16));
          tm = fmaxf(tm, __shfl_xor(tm, 4, 16));
          tm = fmaxf(tm, __shfl_xor(tm, 8, 16));
          float mnew = fmaxf(mrun[i][r], tm);
          float al = __expf(mrun[i][r] - mnew);
          float rs = 0.f;
#pragma unroll
          for (int j = 0; j < 4; j++) {
            float e = __expf(sacc[i][j][r] - mnew);
            sacc[i][j][r] = e;
            rs += e;
          }
          rs += __shfl_xor(rs, 1, 16);
          rs += __shfl_xor(rs, 2, 16);
          rs += __shfl_xor(rs, 4, 16);
          rs += __shfl_xor(rs, 8, 16);
          lrun[i][r] = lrun[i][r] * al + rs;
          mrun[i][r] = mnew;
#pragma unroll
          for (int j = 0; j < 4; j++) oacc[i][j][r] *= al;
          int row = wm + i * 16 + lgrp * 4 + r;
#pragma unroll
          for (int j = 0; j < 4; j++)
            p_s[row * ST + j * 16 + lane16] = f2bf(sacc[i][j][r]);
        }
      }
      __syncthreads();

#pragma unroll
      for (int kc = 0; kc < 2; kc++) {
        bf16x8 ap[2];
#pragma unroll
        for (int i = 0; i < 2; i++)
          ap[i] = *(const bf16x8*)&p_s[(wm + i * 16 + lane16) * ST + kc * 32 + lgrp * 8];
#pragma unroll
        for (int j = 0; j < 4; j++) {
          bf16x8 bv = *(const bf16x8*)&vt_s[(j * 16 + lane16) * ST + kc * 32 + lgrp * 8];
#pragma unroll
          for (int i = 0; i < 2; i++) oacc[i][j] = mfma16(ap[i], bv, oacc[i][j]);
        }
      }
      __syncthreads();
    }

    // unnormalized partial out + per-row m,l
    float* opp = op + ((size_t)(bh * NSPLIT + sp)) * NL * HD;
#pragma unroll
    for (int i = 0; i < 2; i++)
#pragma unroll
      for (int j = 0; j < 4; j++)
#pragma unroll
        for (int r = 0; r < 4; r++) {
          int row = wm + i * 16 + lgrp * 4 + r;
          int dd = j * 16 + lane16;
          opp[(size_t)row * HD + dd] = oacc[i][j][r];
        }
    if (lane16 == 0) {
      const size_t base = (size_t)(bh * NSPLIT + sp) * NL;
#pragma unroll
      for (int i = 0; i < 2; i++)
#pragma unroll
        for (int r = 0; r < 4; r++) {
          int row = wm + i * 16 + lgrp * 4 + r;
          mp[base + row] = mrun[i][r];
          lp[base + row] = lrun[i][r];
        }
    }
  } else {
    // ---------------- k2 landmark softmax path ----------------
    float* cs = (float*)q_s;           // 512 B alias; k2 path never uses q_s
    const int bid = blockIdx.x - BH * NSPLIT;
    const int bh = bid >> 3;
    const int rc = bid & 7;            // 16-row chunk
    const int r = t >> 4;              // local row 0..15
    const int c = t & 15;              // col lane 0..15
    const int row = rc * 16 + r;
    const float* Q = Qlm + ((size_t)bh * NL + row) * HD;
    const float* Kf = Klm + (size_t)bh * NL * HD;
    float* k2p = k2 + (size_t)bh * NL * NL;

    for (int i = t; i < NL; i += 256) cs[i] = 0.f;

    f32x4 q4[16];
#pragma unroll
    for (int d = 0; d < 16; d++) q4[d] = *(const f32x4*)&Q[d * 4];

    float dots[8];
#pragma unroll
    for (int g = 0; g < 8; g++) {
      const float* kr = Kf + (size_t)(c + g * 16) * HD;
      float s = 0.f;
#pragma unroll
      for (int d = 0; d < 16; d++) {
        f32x4 k4 = *(const f32x4*)&kr[d * 4];
        s += q4[d][0] * k4[0];
        s += q4[d][1] * k4[1];
        s += q4[d][2] * k4[2];
        s += q4[d][3] * k4[3];
      }
      dots[g] = s;
    }

    float mx = dots[0];
#pragma unroll
    for (int g = 1; g < 8; g++) mx = fmaxf(mx, dots[g]);
    mx = fmaxf(mx, __shfl_xor(mx, 1, 16));
    mx = fmaxf(mx, __shfl_xor(mx, 2, 16));
    mx = fmaxf(mx, __shfl_xor(mx, 4, 16));
    mx = fmaxf(mx, __shfl_xor(mx, 8, 16));

    float sum = 0.f;
#pragma unroll
    for (int g = 0; g < 8; g++) {
      float e = __expf(dots[g] - mx);
      dots[g] = e;
      sum += e;
    }
    sum += __shfl_xor(sum, 1, 16);
    sum += __shfl_xor(sum, 2, 16);
    sum += __shfl_xor(sum, 4, 16);
    sum += __shfl_xor(sum, 8, 16);
    const float inv = 1.0f / fmaxf(sum, 1e-30f);

    __syncthreads();  // cs init complete
#pragma unroll
    for (int g = 0; g < 8; g++) {
      float p = dots[g] * inv;
      k2p[(size_t)row * NL + c + g * 16] = p;
      atomicAdd(&cs[c + g * 16], p);
    }
    __syncthreads();
    for (int i = t; i < NL; i += 256) atomicAdd(&colsum_g[bh * NL + i], cs[i]);
  }
}

// ---------------------------------------------------------------------------
// Kernel 4b: combine NSPLIT flash partials -> k3v fp32 (2048 blocks — the
// high-occupancy read of the 33.5 MB partials).
// ---------------------------------------------------------------------------
__global__ __launch_bounds__(256) void k3v_combine(
    const float* __restrict__ op, const float* __restrict__ mp,
    const float* __restrict__ lp, float* __restrict__ k3v)
{
  const int idx = blockIdx.x * 256 + threadIdx.x;  // over BH*NL*HD
  const int dd = idx & 63;
  const int row = (idx >> 6) & 127;
  const int bh = idx >> 13;
  (void)dd;
  float m = -3.0e38f;
  float ms[NSPLIT];
#pragma unroll
  for (int s = 0; s < NSPLIT; s++) {
    ms[s] = mp[(size_t)(bh * NSPLIT + s) * NL + row];
    m = fmaxf(m, ms[s]);
  }
  float o = 0.f, ltot = 0.f;
#pragma unroll
  for (int s = 0; s < NSPLIT; s++) {
    float sc = __expf(ms[s] - m);
    ltot += lp[(size_t)(bh * NSPLIT + s) * NL + row] * sc;
    o += op[((size_t)(bh * NSPLIT + s) * NL + row) * HD + dd] * sc;
  }
  k3v[idx] = clampf(o / fmaxf(ltot, 1e-30f));
}

// ---------------------------------------------------------------------------
// Kernel 5: Newton-Schulz pseudo-inverse, 6 iterations, hi/lo-split bf16 MFMA,
// fully LDS-resident (8-barrier/iter form).  Prologue: inline alpha =
// max(colsum_g).  Tail: W2 = Vinv @ k3v.
// ---------------------------------------------------------------------------
__global__ __launch_bounds__(512, 1) void ns_kernel(
    const float* __restrict__ k2, const float* __restrict__ colsum_g,
    const float* __restrict__ k3v, unsigned short* __restrict__ w2t)
{
  constexpr int VST = 132;   // fp32 row stride: 132 mod 32 = 4 -> 2-way (free) banks
  constexpr int BST = 136;   // bf16 row stride: 68 dwords -> uniform b128 starts
  __shared__ __align__(16) float Vf[NL * VST];    // 67.6 KB
  __shared__ __align__(16) short Bth[NL * BST];   // 34.8 KB
  __shared__ __align__(16) short Btl[NL * BST];   // 34.8 KB  (total ~137 KB < 160 KB)
  __shared__ float wmx[8];
  __shared__ float amax_s;

  const int bh = blockIdx.x, t = threadIdx.x;
  const int w = t >> 6, l = t & 63;
  const int lane16 = l & 15, lgrp = l >> 4;
  const float* K2 = k2 + (size_t)bh * NL * NL;

  // --- inline alpha: max over all colsums (32 KB, L2-served) ---
  float am = 0.f;  // colsums are sums of softmax probs >= 0
  for (int i = t; i < BH * NL; i += 512) am = fmaxf(am, colsum_g[i]);
#pragma unroll
  for (int o = 1; o < 64; o <<= 1) am = fmaxf(am, __shfl_xor(am, o, 64));
  if (l == 0) wmx[w] = am;
  __syncthreads();
  if (t == 0) {
    float m = wmx[0];
#pragma unroll
    for (int i = 1; i < 8; i++) m = fmaxf(m, wmx[i]);
    amax_s = m;
  }
  __syncthreads();
  const float inva = 1.0f / fmaxf(amax_s, 1e-30f);

  // --- K2 A-fragments (hi/lo) into registers, once (64 VGPRs) ---
  bf16x8 k2hi[4], k2lo[4];
#pragma unroll
  for (int kk = 0; kk < 4; kk++) {
    const float* ap = K2 + (size_t)(w * 16 + lane16) * NL + kk * 32 + lgrp * 8;
    f32x4 a0 = *(const f32x4*)ap;
    f32x4 a1 = *(const f32x4*)(ap + 4);
    float av[8] = {a0[0], a0[1], a0[2], a0[3], a1[0], a1[1], a1[2], a1[3]};
    split8(av, k2hi[kk], k2lo[kk]);
  }

  // --- init: V = clamp(K2^T * inva) -> Vf row-major; Bt = V^T = clamp(K2*inva)
  for (int i = t; i < NL * NL; i += 512) {
    int rr = i >> 7, cc = i & 127;
    float v = clampf(K2[(size_t)cc * NL + rr] * inva);
    Vf[rr * VST + cc] = v;
    short hi, lo; split1(v, hi, lo);
    Bth[cc * BST + rr] = hi;
    Btl[cc * BST + rr] = lo;
  }
  __syncthreads();

  f32x4 macc[8], vacc[8];

  // macc = A @ B  with A-fragments in registers, B = Bt (transposed hi/lo)
  auto mmA = [&](const bf16x8* ahi, const bf16x8* alo) {
#pragma unroll
    for (int j = 0; j < 8; j++) macc[j] = f32x4{0.f, 0.f, 0.f, 0.f};
#pragma unroll
    for (int kk = 0; kk < 4; kk++) {
#pragma unroll
      for (int j = 0; j < 8; j++) {
        const int bo = (j * 16 + lane16) * BST + kk * 32 + lgrp * 8;
        bf16x8 bh_ = *(const bf16x8*)&Bth[bo];
        bf16x8 bl_ = *(const bf16x8*)&Btl[bo];
        macc[j] = mfma16(alo[kk], bh_, macc[j]);
        macc[j] = mfma16(ahi[kk], bl_, macc[j]);
        macc[j] = mfma16(ahi[kk], bh_, macc[j]);
      }
    }
  };

  // macc = Vf @ B (A rows = this wave's 16 rows of Vf, split on the fly)
  auto mmV = [&]() {
    bf16x8 ahi[4], alo[4];
#pragma unroll
    for (int kk = 0; kk < 4; kk++) {
      const float* ap = &Vf[(w * 16 + lane16) * VST + kk * 32 + lgrp * 8];
      f32x4 a0 = *(const f32x4*)ap;
      f32x4 a1 = *(const f32x4*)(ap + 4);
      float av[8] = {a0[0], a0[1], a0[2], a0[3], a1[0], a1[1], a1[2], a1[3]};
      split8(av, ahi[kk], alo[kk]);
    }
    mmA(ahi, alo);
  };

  // Bt <- clamp(macc)^T  (packed b64 writes: 4 consecutive rows per lane)
  auto writeBt = [&]() {
#pragma unroll
    for (int j = 0; j < 8; j++) {
      short4v hv, lv;
#pragma unroll
      for (int r = 0; r < 4; r++) {
        float c = clampf(macc[j][r]);
        short hi, lo; split1(c, hi, lo);
        hv[r] = hi; lv[r] = lo;
      }
      const int base = (j * 16 + lane16) * BST + w * 16 + lgrp * 4;
      *(short4v*)&Bth[base] = hv;
      *(short4v*)&Btl[base] = lv;
    }
  };

  for (int it = 0; it < 6; it++) {
    // KV = K2 @ V   (B = Bt holding V^T)
    mmA(k2hi, k2lo);
    __syncthreads();              // all waves done reading Bt(V^T)
    writeBt();                    // Bt <- KV^T (clamped), B for mm2..mm4
    __syncthreads();

    // M1 = V @ KV ; vacc = 3.25*V - 3.75*M1
    mmV();
#pragma unroll
    for (int j = 0; j < 8; j++)
#pragma unroll
      for (int r = 0; r < 4; r++)
        vacc[j][r] = 3.25f * Vf[(w * 16 + lgrp * 4 + r) * VST + j * 16 + lane16]
                   - 3.75f * macc[j][r];
    __syncthreads();
#pragma unroll
    for (int j = 0; j < 8; j++)
#pragma unroll
      for (int r = 0; r < 4; r++)
        Vf[(w * 16 + lgrp * 4 + r) * VST + j * 16 + lane16] = clampf(macc[j][r]);
    __syncthreads();

    // M2 = M1 @ KV ; vacc += 1.75*M2
    mmV();
#pragma unroll
    for (int j = 0; j < 8; j++)
#pragma unroll
      for (int r = 0; r < 4; r++) vacc[j][r] += 1.75f * macc[j][r];
    __syncthreads();
#pragma unroll
    for (int j = 0; j < 8; j++)
#pragma unroll
      for (int r = 0; r < 4; r++)
        Vf[(w * 16 + lgrp * 4 + r) * VST + j * 16 + lane16] = clampf(macc[j][r]);
    __syncthreads();

    // M3 = M2 @ KV ; V_new = clamp(vacc - 0.25*M3) -> Vf + Bt (for next iter)
    mmV();
    __syncthreads();              // all waves done reading Bt(KV^T) + Vf(M2)
#pragma unroll
    for (int j = 0; j < 8; j++) {
      short4v hv, lv;
#pragma unroll
      for (int r = 0; r < 4; r++) {
        float v = clampf(vacc[j][r] - 0.25f * macc[j][r]);
        Vf[(w * 16 + lgrp * 4 + r) * VST + j * 16 + lane16] = v;
        short hi, lo; split1(v, hi, lo);
        hv[r] = hi; lv[r] = lo;
      }
      const int base = (j * 16 + lane16) * BST + w * 16 + lgrp * 4;
      *(short4v*)&Bth[base] = hv;
      *(short4v*)&Btl[base] = lv;
    }
    __syncthreads();
  }

  // ------- tail: W2 = Vinv @ k3v ;  w2t[dd][m] = W2[m][dd] -------
  const float* kvp = k3v + (size_t)bh * NL * HD;
  for (int i = t; i < NL * HD; i += 512) {
    int rr = i >> 6, dd = i & 63;
    float f = kvp[i];
    short hi, lo; split1(f, hi, lo);
    Bth[dd * BST + rr] = hi;
    Btl[dd * BST + rr] = lo;
  }
  __syncthreads();

  const int wr = (w & 3);    // dd row-tile (4 x 16 = 64 rows)
  const int wc = (w >> 2);   // m half (2 x 64 cols)
  f32x4 oacc[4];
#pragma unroll
  for (int j = 0; j < 4; j++) oacc[j] = f32x4{0.f, 0.f, 0.f, 0.f};
#pragma unroll
  for (int kk = 0; kk < 4; kk++) {
    const int ao = (wr * 16 + lane16) * BST + kk * 32 + lgrp * 8;
    bf16x8 ahi = *(const bf16x8*)&Bth[ao];
    bf16x8 alo = *(const bf16x8*)&Btl[ao];
#pragma unroll
    for (int j = 0; j < 4; j++) {
      const float* bp = &Vf[((wc * 4 + j) * 16 + lane16) * VST + kk * 32 + lgrp * 8];
      f32x4 b0 = *(const f32x4*)bp;
      f32x4 b1 = *(const f32x4*)(bp + 4);
      float bvv[8] = {b0[0], b0[1], b0[2], b0[3], b1[0], b1[1], b1[2], b1[3]};
      bf16x8 bhv, blv;
      split8(bvv, bhv, blv);
      oacc[j] = mfma16(alo, bhv, oacc[j]);
      oacc[j] = mfma16(ahi, blv, oacc[j]);
      oacc[j] = mfma16(ahi, bhv, oacc[j]);
    }
  }
  unsigned short* outp = w2t + (size_t)bh * HD * NL;
#pragma unroll
  for (int j = 0; j < 4; j++)
#pragma unroll
    for (int r = 0; r < 4; r++) {
      int dd = wr * 16 + lgrp * 4 + r;
      int m  = (wc * 4 + j) * 16 + lane16;
      outp[(size_t)dd * NL + m] = (unsigned short)f2bf(clampf(oacc[j][r]));
    }
}

// ---------------------------------------------------------------------------
// Kernel 7: out = softmax_rows(Q @ Klm^T) @ W2 -> FP32 output.
// ---------------------------------------------------------------------------
__global__ __launch_bounds__(256, 2) void final_kernel(
    const unsigned short* __restrict__ Q, const unsigned short* __restrict__ Klmb,
    const unsigned short* __restrict__ w2t, float* __restrict__ outp)
{
  constexpr int KSD = 72;
  constexpr int PSD = 136;
  __shared__ __align__(16) short klm_s[NL * KSD];
  __shared__ __align__(16) short p_s[NL * PSD];

  const int bid = blockIdx.x;
  const int bh = bid >> 5, lt = bid & 31;
  const int l0 = lt * NL;
  const int t = threadIdx.x, w = t >> 6, l = t & 63;
  const int lane16 = l & 15, lgrp = l >> 4;
  const int wm = w * 32;
  const unsigned short* Qp = Q + (size_t)bh * LL * HD;
  const unsigned short* Kp = Klmb + (size_t)bh * NL * HD;
  const unsigned short* Wp = w2t + (size_t)bh * HD * NL;

  for (int i = t; i < NL * HD / 4; i += 256) {
    int flat = i * 4, rr = flat >> 6, dd = flat & 63;
    *(uint2*)&klm_s[rr * KSD + dd] = *(const uint2*)&Kp[flat];
  }
  __syncthreads();

  f32x4 sacc[2][8];
#pragma unroll
  for (int i = 0; i < 2; i++)
#pragma unroll
    for (int j = 0; j < 8; j++) sacc[i][j] = f32x4{0.f, 0.f, 0.f, 0.f};
#pragma unroll
  for (int kc = 0; kc < 2; kc++) {
    bf16x8 aq[2];
#pragma unroll
    for (int i = 0; i < 2; i++)
      aq[i] = *(const bf16x8*)&Qp[(size_t)(l0 + wm + i * 16 + lane16) * HD + kc * 32 + lgrp * 8];
#pragma unroll
    for (int j = 0; j < 8; j++) {
      bf16x8 bk = *(const bf16x8*)&klm_s[(j * 16 + lane16) * KSD + kc * 32 + lgrp * 8];
#pragma unroll
      for (int i = 0; i < 2; i++) sacc[i][j] = mfma16(aq[i], bk, sacc[i][j]);
    }
  }

#pragma unroll
  for (int i = 0; i < 2; i++) {
#pragma unroll
    for (int r = 0; r < 4; r++) {
      float mx = -1e30f;
#pragma unroll
      for (int j = 0; j < 8; j++) mx = fmaxf(mx, sacc[i][j][r]);
      mx = fmaxf(mx, __shfl_xor(mx, 1, 16));
      mx = fmaxf(mx, __shfl_xor(mx, 2, 16));
      mx = fmaxf(mx, __shfl_xor(mx, 4, 16));
      mx = fmaxf(mx, __shfl_xor(mx, 8, 16));
      float sum = 0.f;
#pragma unroll
      for (int j = 0; j < 8; j++) {
        float e = __expf(sacc[i][j][r] - mx);
        sacc[i][j][r] = e;
        sum += e;
      }
      sum += __shfl_xor(sum, 1, 16);
      sum += __shfl_xor(sum, 2, 16);
      sum += __shfl_xor(sum, 4, 16);
      sum += __shfl_xor(sum, 8, 16);
      float inv = 1.0f / fmaxf(sum, 1e-30f);
      int row = wm + i * 16 + lgrp * 4 + r;
#pragma unroll
      for (int j = 0; j < 8; j++)
        p_s[row * PSD + j * 16 + lane16] = f2bf(sacc[i][j][r] * inv);
    }
  }
  __syncthreads();

  f32x4 oacc[2][4];
#pragma unroll
  for (int i = 0; i < 2; i++)
#pragma unroll
    for (int j = 0; j < 4; j++) oacc[i][j] = f32x4{0.f, 0.f, 0.f, 0.f};
#pragma unroll
  for (int kc = 0; kc < 4; kc++) {
    bf16x8 ap[2];
#pragma unroll
    for (int i = 0; i < 2; i++)
      ap[i] = *(const bf16x8*)&p_s[(wm + i * 16 + lane16) * PSD + kc * 32 + lgrp * 8];
#pragma unroll
    for (int j = 0; j < 4; j++) {
      bf16x8 bw = *(const bf16x8*)&Wp[(size_t)(j * 16 + lane16) * NL + kc * 32 + lgrp * 8];
#pragma unroll
      for (int i = 0; i < 2; i++) oacc[i][j] = mfma16(ap[i], bw, oacc[i][j]);
    }
  }

  const int b = bh >> 4, h = bh & 15;
#pragma unroll
  for (int i = 0; i < 2; i++)
#pragma unroll
    for (int j = 0; j < 4; j++)
#pragma unroll
      for (int r = 0; r < 4; r++) {
        int row = wm + i * 16 + lgrp * 4 + r;
        int dd = j * 16 + lane16;
        outp[((size_t)b * LL + l0 + row) * DM + h * HD + dd] = oacc[i][j][r];  // FP32 store
      }
}

// ---------------------------------------------------------------------------
extern "C" void kernel_launch(void* const* d_in, const int* in_sizes, int n_in,
                              void* d_out, int out_size, void* d_ws, size_t ws_size,
                              hipStream_t stream) {
  (void)in_sizes; (void)n_in; (void)out_size; (void)ws_size;
  float* outp = (float*)d_out;  // reference output dtype = float32

  char* ws = (char*)d_ws;
  size_t off = 0;
  auto alloc = [&](size_t bytes) -> void* {
    void* p = ws + off;
    off += (bytes + 255) & ~(size_t)255;
    return p;
  };
  float* colsum_g = (float*)alloc((size_t)BH * NL * 4);
  float* Qlm = (float*)alloc((size_t)BH * NL * HD * 4);
  float* Klm = (float*)alloc((size_t)BH * NL * HD * 4);
  unsigned short* Qlmb = (unsigned short*)alloc((size_t)BH * NL * HD * 2);
  unsigned short* Klmb = (unsigned short*)alloc((size_t)BH * NL * HD * 2);
  float* k2 = (float*)alloc((size_t)BH * NL * NL * 4);
  float* k3v = (float*)alloc((size_t)BH * NL * HD * 4);
  unsigned short* w2t = (unsigned short*)alloc((size_t)BH * HD * NL * 2);
  unsigned short* Wb = (unsigned short*)alloc((size_t)3 * DM * DM * 2);
  float* bb = (float*)alloc((size_t)3 * DM * 4);
  // union region: xb (bf16 x, 33.6 MB — dead after proj) aliases the k3v
  // split-K partials op/mp/lp (34.6 MB at NSPLIT=16 — written after proj).
  const size_t OP_BYTES = (size_t)BH * NSPLIT * NL * HD * 4;           // 33.55 MB
  const size_t ML_BYTES = (size_t)BH * NSPLIT * NL * 4;                // 0.5 MB
  const size_t XB_BYTES = (size_t)4 * LL * DM * 2;                     // 33.55 MB
  const size_t UB_BYTES = OP_BYTES + 2 * ML_BYTES + 512;
  char* ub = (char*)alloc(UB_BYTES > XB_BYTES ? UB_BYTES : XB_BYTES);
  unsigned short* xb = (unsigned short*)ub;
  float* op = (float*)ub;
  float* mp = (float*)(ub + OP_BYTES);
  float* lp = mp + (size_t)BH * NSPLIT * NL;
  const size_t QKV = (size_t)BH * LL * HD;
  unsigned short* Qb = (unsigned short*)alloc(QKV * 2);
  unsigned short* Kb = (unsigned short*)alloc(QKV * 2);
  unsigned short* Vb = (unsigned short*)alloc(QKV * 2);

  hipMemsetAsync(colsum_g, 0, (size_t)BH * NL * 4, stream);
  cvt_kernel<<<3585, 256, 0, stream>>>(
      d_in[0], d_in[1], d_in[3], d_in[5], d_in[2], d_in[4], d_in[6],
      xb, Wb, bb);
  proj_kernel<<<128 * 24, 256, 0, stream>>>(xb, Wb, bb, Qb, Kb, Vb,
                                            Qlm, Klm, Qlmb, Klmb);
  mid_kernel<<<BH * NSPLIT + BH * 8, 256, 0, stream>>>(
      Qlmb, Kb, Vb, op, mp, lp, Qlm, Klm, k2, colsum_g);
  k3v_combine<<<BH * NL * HD / 256, 256, 0, stream>>>(op, mp, lp, k3v);
  ns_kernel<<<BH, 512, 0, stream>>>(k2, colsum_g, k3v, w2t);
  final_kernel<<<BH * 32, 256, 0, stream>>>(Qb, Klmb, w2t, outp);
}